// Round 1
// baseline (2756.381 us; speedup 1.0000x reference)
//
#include <hip/hip_runtime.h>

#define NN 100000
#define NE 1600000

// ---------------- degree / norm ----------------
__global__ void k_deg_init(float* __restrict__ deg) {
    int i = blockIdx.x * 256 + threadIdx.x;
    if (i < NN) deg[i] = 1.0f;   // self-loop contribution
}

__global__ void k_deg_count(const int* __restrict__ dst, float* __restrict__ deg) {
    int e = blockIdx.x * 256 + threadIdx.x;
    if (e < NE) unsafeAtomicAdd(&deg[dst[e]], 1.0f);
}

__global__ void k_dinv(float* __restrict__ deg) {
    int i = blockIdx.x * 256 + threadIdx.x;
    if (i < NN) deg[i] = rsqrtf(deg[i]);   // deg >= 1 always (self loop)
}

__global__ void k_norm(const int* __restrict__ src, const int* __restrict__ dst,
                       const float* __restrict__ dinv, float* __restrict__ norm) {
    int e = blockIdx.x * 256 + threadIdx.x;
    if (e < NE) norm[e] = dinv[src[e]] * dinv[dst[e]];
}

// ---------------- GEMM1: t1 = x @ W1   [NN,128]x[128,64] ----------------
__global__ __launch_bounds__(256) void k_gemm1(const float* __restrict__ x,
                                               const float* __restrict__ W1,
                                               float* __restrict__ t1) {
    __shared__ float xs[64][132];     // +4 pad: bank = (4r+k)%32
    __shared__ float ws[128 * 64];
    const int t = threadIdx.x;
    const int row0 = blockIdx.x * 64;
    const int nrows = min(64, NN - row0);

    // stage W1: 8192 floats = 2048 float4
    #pragma unroll
    for (int i = 0; i < 8; ++i) {
        int f = t + i * 256;
        *(float4*)&ws[f * 4] = ((const float4*)W1)[f];
    }
    // stage x tile: 64 rows x 128 = 2048 float4
    #pragma unroll
    for (int i = 0; i < 8; ++i) {
        int f = t + i * 256;
        int r = f >> 5, k4 = f & 31;
        float4 v = make_float4(0.f, 0.f, 0.f, 0.f);
        if (r < nrows) v = ((const float4*)(x + (size_t)(row0 + r) * 128))[k4];
        *(float4*)&xs[r][k4 * 4] = v;
    }
    __syncthreads();

    const int tc = t & 15;   // col group: cols tc*4..tc*4+3
    const int tr = t >> 4;   // row group: rows tr*4..tr*4+3
    float acc[4][4];
    #pragma unroll
    for (int i = 0; i < 4; ++i)
        #pragma unroll
        for (int j = 0; j < 4; ++j) acc[i][j] = 0.f;

    #pragma unroll 4
    for (int k = 0; k < 128; ++k) {
        float4 wv = *(const float4*)&ws[k * 64 + tc * 4];
        #pragma unroll
        for (int i = 0; i < 4; ++i) {
            float xv = xs[tr * 4 + i][k];
            acc[i][0] += xv * wv.x; acc[i][1] += xv * wv.y;
            acc[i][2] += xv * wv.z; acc[i][3] += xv * wv.w;
        }
    }
    #pragma unroll
    for (int i = 0; i < 4; ++i) {
        int r = tr * 4 + i;
        if (r < nrows) {
            float4 o = make_float4(acc[i][0], acc[i][1], acc[i][2], acc[i][3]);
            *(float4*)&t1[(size_t)(row0 + r) * 64 + tc * 4] = o;
        }
    }
}

// ---------------- self-loop init: agg = h * dinv^2 ----------------
__global__ void k_selfinit(const float* __restrict__ h, const float* __restrict__ dinv,
                           float* __restrict__ agg) {
    int idx = blockIdx.x * 256 + threadIdx.x;      // over NN*16 float4s
    if (idx >= NN * 16) return;
    int i = idx >> 4;
    float d = dinv[i];
    float w = d * d;
    float4 v = ((const float4*)h)[idx];
    float4 o = make_float4(v.x * w, v.y * w, v.z * w, v.w * w);
    ((float4*)agg)[idx] = o;
}

// ---------------- edge scatter: agg[dst] += h[src] * norm ----------------
__global__ void k_scatter(const int* __restrict__ src, const int* __restrict__ dst,
                          const float* __restrict__ norm, const float* __restrict__ h,
                          float* __restrict__ agg) {
    int idx = blockIdx.x * 256 + threadIdx.x;      // 16 threads per edge
    int e = idx >> 4;
    if (e >= NE) return;
    int c4 = idx & 15;
    int s = src[e], d = dst[e];
    float w = norm[e];
    float4 v = ((const float4*)(h + (size_t)s * 64))[c4];
    float* o = agg + (size_t)d * 64 + c4 * 4;
    unsafeAtomicAdd(o + 0, v.x * w);
    unsafeAtomicAdd(o + 1, v.y * w);
    unsafeAtomicAdd(o + 2, v.z * w);
    unsafeAtomicAdd(o + 3, v.w * w);
}

// ---------------- h1 = relu(agg + b1) ----------------
__global__ void k_relu_bias(const float* __restrict__ agg, const float* __restrict__ b1,
                            float* __restrict__ h) {
    int idx = blockIdx.x * 256 + threadIdx.x;      // over NN*16 float4s
    if (idx >= NN * 16) return;
    int c4 = idx & 15;
    float4 b = ((const float4*)b1)[c4];
    float4 v = ((const float4*)agg)[idx];
    float4 o = make_float4(fmaxf(v.x + b.x, 0.f), fmaxf(v.y + b.y, 0.f),
                           fmaxf(v.z + b.z, 0.f), fmaxf(v.w + b.w, 0.f));
    ((float4*)h)[idx] = o;
}

// ---------------- GEMM2: out1 = agg@W2+b2, out2 = agg@W3+b3 ----------------
__global__ __launch_bounds__(256) void k_gemm2(const float* __restrict__ agg,
                                               const float* __restrict__ W2, const float* __restrict__ b2,
                                               const float* __restrict__ W3, const float* __restrict__ b3,
                                               float* __restrict__ out) {
    __shared__ float as_[64][68];     // +4 pad
    __shared__ float wc[64 * 64];
    __shared__ float bc[64];
    const int t = threadIdx.x;
    const int row0 = blockIdx.x * 64;
    const int nrows = min(64, NN - row0);

    // stage combined weights: wc[k][c] = c<32 ? W2[k][c] : W3[k][c-32]
    #pragma unroll
    for (int i = 0; i < 16; ++i) {
        int f = t + i * 256;           // 0..4095
        int k = f >> 6, c = f & 63;
        wc[f] = (c < 32) ? W2[k * 32 + c] : W3[k * 32 + (c - 32)];
    }
    if (t < 64) bc[t] = (t < 32) ? b2[t] : b3[t - 32];
    // stage agg tile: 64 rows x 64 = 1024 float4
    #pragma unroll
    for (int i = 0; i < 4; ++i) {
        int f = t + i * 256;
        int r = f >> 4, c4 = f & 15;
        float4 v = make_float4(0.f, 0.f, 0.f, 0.f);
        if (r < nrows) v = ((const float4*)(agg + (size_t)(row0 + r) * 64))[c4];
        *(float4*)&as_[r][c4 * 4] = v;
    }
    __syncthreads();

    const int tc = t & 15;
    const int tr = t >> 4;
    float acc[4][4];
    #pragma unroll
    for (int i = 0; i < 4; ++i)
        #pragma unroll
        for (int j = 0; j < 4; ++j) acc[i][j] = 0.f;

    #pragma unroll 4
    for (int k = 0; k < 64; ++k) {
        float4 wv = *(const float4*)&wc[k * 64 + tc * 4];
        #pragma unroll
        for (int i = 0; i < 4; ++i) {
            float xv = as_[tr * 4 + i][k];
            acc[i][0] += xv * wv.x; acc[i][1] += xv * wv.y;
            acc[i][2] += xv * wv.z; acc[i][3] += xv * wv.w;
        }
    }
    const int c0 = tc * 4;
    float4 bias = *(float4*)&bc[c0];
    #pragma unroll
    for (int i = 0; i < 4; ++i) {
        int r = tr * 4 + i;
        if (r < nrows) {
            float4 o = make_float4(acc[i][0] + bias.x, acc[i][1] + bias.y,
                                   acc[i][2] + bias.z, acc[i][3] + bias.w);
            size_t row = (size_t)(row0 + r);
            float* p = (tc < 8) ? (out + row * 32 + c0)
                                : (out + (size_t)NN * 32 + row * 32 + (c0 - 32));
            *(float4*)p = o;
        }
    }
}

extern "C" void kernel_launch(void* const* d_in, const int* in_sizes, int n_in,
                              void* d_out, int out_size, void* d_ws, size_t ws_size,
                              hipStream_t stream) {
    const float* x  = (const float*)d_in[0];
    const int* edges = (const int*)d_in[1];
    const float* W1 = (const float*)d_in[2];
    const float* b1 = (const float*)d_in[3];
    const float* W2 = (const float*)d_in[4];
    const float* b2 = (const float*)d_in[5];
    const float* W3 = (const float*)d_in[6];
    const float* b3 = (const float*)d_in[7];
    float* out = (float*)d_out;

    const int* srcs = edges;            // edges[0]
    const int* dsts = edges + NE;       // edges[1]

    float* ws   = (float*)d_ws;
    float* deg  = ws;                   // NN floats (becomes dinv in place)
    float* norm = ws + NN;              // NE floats
    float* agg  = ws + NN + NE;         // NN*64 floats (16B aligned: (NN+NE)*4 % 16 == 0)
    float* t1   = out;                  // reuse d_out as [NN,64] scratch; fully overwritten by k_gemm2

    dim3 blk(256);
    k_deg_init<<<(NN + 255) / 256, blk, 0, stream>>>(deg);
    k_deg_count<<<(NE + 255) / 256, blk, 0, stream>>>(dsts, deg);
    k_dinv<<<(NN + 255) / 256, blk, 0, stream>>>(deg);
    k_norm<<<(NE + 255) / 256, blk, 0, stream>>>(srcs, dsts, deg, norm);

    k_gemm1<<<(NN + 63) / 64, blk, 0, stream>>>(x, W1, t1);

    k_selfinit<<<(NN * 16 + 255) / 256, blk, 0, stream>>>(t1, deg, agg);
    k_scatter<<<(NE * 16 + 255) / 256, blk, 0, stream>>>(srcs, dsts, norm, t1, agg);
    k_relu_bias<<<(NN * 16 + 255) / 256, blk, 0, stream>>>(agg, b1, t1);

    k_selfinit<<<(NN * 16 + 255) / 256, blk, 0, stream>>>(t1, deg, agg);
    k_scatter<<<(NE * 16 + 255) / 256, blk, 0, stream>>>(srcs, dsts, norm, t1, agg);

    k_gemm2<<<(NN + 63) / 64, blk, 0, stream>>>(agg, W2, b2, W3, b3, out);
}

// Round 2
// 366.884 us; speedup vs baseline: 7.5129x; 7.5129x over previous
//
#include <hip/hip_runtime.h>

#define NN 100000
#define NE 1600000
#define SCAN_NBLK 98   // ceil(NN/1024)

// ---------------- CSR build ----------------
__global__ void k_count(const int* __restrict__ dst, int* __restrict__ cnt) {
    int e = blockIdx.x * 256 + threadIdx.x;
    if (e < NE) atomicAdd(&cnt[dst[e]], 1);
}

__global__ void k_dinvk(const int* __restrict__ cnt, float* __restrict__ dinv) {
    int i = blockIdx.x * 256 + threadIdx.x;
    if (i < NN) dinv[i] = rsqrtf(1.0f + (float)cnt[i]);  // +1 self loop
}

// block scans 1024 counts (4/thread), writes exclusive prefixes + block sum
__global__ __launch_bounds__(256) void k_scan1(const int* __restrict__ cnt,
                                               int* __restrict__ off,
                                               int* __restrict__ blksum) {
    __shared__ int sh[256];
    int t = threadIdx.x, b = blockIdx.x;
    int base = b * 1024 + t * 4;
    int v0 = (base + 0 < NN) ? cnt[base + 0] : 0;
    int v1 = (base + 1 < NN) ? cnt[base + 1] : 0;
    int v2 = (base + 2 < NN) ? cnt[base + 2] : 0;
    int v3 = (base + 3 < NN) ? cnt[base + 3] : 0;
    int tsum = v0 + v1 + v2 + v3;
    sh[t] = tsum;
    __syncthreads();
    for (int d = 1; d < 256; d <<= 1) {
        int x = (t >= d) ? sh[t - d] : 0;
        __syncthreads();
        sh[t] += x;
        __syncthreads();
    }
    int excl = sh[t] - tsum;
    if (base + 0 < NN) off[base + 0] = excl;
    if (base + 1 < NN) off[base + 1] = excl + v0;
    if (base + 2 < NN) off[base + 2] = excl + v0 + v1;
    if (base + 3 < NN) off[base + 3] = excl + v0 + v1 + v2;
    if (t == 255) blksum[b] = sh[255];
}

__global__ __launch_bounds__(256) void k_scan2(int* __restrict__ blksum) {
    __shared__ int sh[256];
    int t = threadIdx.x;
    int v = (t < SCAN_NBLK) ? blksum[t] : 0;
    sh[t] = v;
    __syncthreads();
    for (int d = 1; d < 256; d <<= 1) {
        int x = (t >= d) ? sh[t - d] : 0;
        __syncthreads();
        sh[t] += x;
        __syncthreads();
    }
    if (t < SCAN_NBLK) blksum[t] = sh[t] - v;  // exclusive
}

__global__ void k_scan3(int* __restrict__ off, const int* __restrict__ blksum) {
    int i = blockIdx.x * 256 + threadIdx.x;
    if (i < NN) off[i] += blksum[i >> 10];
    if (i == 0) off[NN] = NE;
}

__global__ void k_fill(const int* __restrict__ src, const int* __restrict__ dst,
                       const int* __restrict__ off, int* __restrict__ cursor,
                       int* __restrict__ csr) {
    int e = blockIdx.x * 256 + threadIdx.x;
    if (e < NE) {
        int d = dst[e];
        int p = atomicAdd(&cursor[d], 1);
        csr[off[d] + p] = src[e];
    }
}

// ---------------- GEMM1: t1 = x @ W1   [NN,128]x[128,64] ----------------
__global__ __launch_bounds__(256) void k_gemm1(const float* __restrict__ x,
                                               const float* __restrict__ W1,
                                               float* __restrict__ t1) {
    __shared__ float xs[64][132];
    __shared__ float ws[128 * 64];
    const int t = threadIdx.x;
    const int row0 = blockIdx.x * 64;
    const int nrows = min(64, NN - row0);

    #pragma unroll
    for (int i = 0; i < 8; ++i) {
        int f = t + i * 256;
        *(float4*)&ws[f * 4] = ((const float4*)W1)[f];
    }
    #pragma unroll
    for (int i = 0; i < 8; ++i) {
        int f = t + i * 256;
        int r = f >> 5, k4 = f & 31;
        float4 v = make_float4(0.f, 0.f, 0.f, 0.f);
        if (r < nrows) v = ((const float4*)(x + (size_t)(row0 + r) * 128))[k4];
        *(float4*)&xs[r][k4 * 4] = v;
    }
    __syncthreads();

    const int tc = t & 15;
    const int tr = t >> 4;
    float acc[4][4];
    #pragma unroll
    for (int i = 0; i < 4; ++i)
        #pragma unroll
        for (int j = 0; j < 4; ++j) acc[i][j] = 0.f;

    #pragma unroll 4
    for (int k = 0; k < 128; ++k) {
        float4 wv = *(const float4*)&ws[k * 64 + tc * 4];
        #pragma unroll
        for (int i = 0; i < 4; ++i) {
            float xv = xs[tr * 4 + i][k];
            acc[i][0] += xv * wv.x; acc[i][1] += xv * wv.y;
            acc[i][2] += xv * wv.z; acc[i][3] += xv * wv.w;
        }
    }
    #pragma unroll
    for (int i = 0; i < 4; ++i) {
        int r = tr * 4 + i;
        if (r < nrows) {
            float4 o = make_float4(acc[i][0], acc[i][1], acc[i][2], acc[i][3]);
            *(float4*)&t1[(size_t)(row0 + r) * 64 + tc * 4] = o;
        }
    }
}

// ---------------- gather aggregation ----------------
// agg[n] = dinv[n] * ( dinv[n]*h[n] + sum_{e: dst=n} dinv[src]*h[src] )
// RELU: out = relu(agg + b); else out = agg.
template <bool RELU>
__global__ __launch_bounds__(256) void k_gather(const int* __restrict__ off,
                                                const int* __restrict__ csr,
                                                const float* __restrict__ dinv,
                                                const float* __restrict__ h,
                                                const float* __restrict__ bias,
                                                float* __restrict__ outp) {
    int idx = blockIdx.x * 256 + threadIdx.x;   // 16 lanes per node
    int n = idx >> 4;
    if (n >= NN) return;
    int c4 = idx & 15;
    float dn = dinv[n];
    float4 hv = ((const float4*)(h + (size_t)n * 64))[c4];
    float4 acc = make_float4(hv.x * dn, hv.y * dn, hv.z * dn, hv.w * dn);
    int b = off[n], e = off[n + 1];
    for (int i = b; i < e; ++i) {
        int s = csr[i];
        float w = dinv[s];
        float4 v = ((const float4*)(h + (size_t)s * 64))[c4];
        acc.x += w * v.x; acc.y += w * v.y;
        acc.z += w * v.z; acc.w += w * v.w;
    }
    float4 o = make_float4(acc.x * dn, acc.y * dn, acc.z * dn, acc.w * dn);
    if (RELU) {
        float4 bv = ((const float4*)bias)[c4];
        o.x = fmaxf(o.x + bv.x, 0.f); o.y = fmaxf(o.y + bv.y, 0.f);
        o.z = fmaxf(o.z + bv.z, 0.f); o.w = fmaxf(o.w + bv.w, 0.f);
    }
    ((float4*)outp)[idx] = o;
}

// ---------------- GEMM2: out1 = agg@W2+b2, out2 = agg@W3+b3 ----------------
__global__ __launch_bounds__(256) void k_gemm2(const float* __restrict__ agg,
                                               const float* __restrict__ W2, const float* __restrict__ b2,
                                               const float* __restrict__ W3, const float* __restrict__ b3,
                                               float* __restrict__ out) {
    __shared__ float as_[64][68];
    __shared__ float wc[64 * 64];
    __shared__ float bc[64];
    const int t = threadIdx.x;
    const int row0 = blockIdx.x * 64;
    const int nrows = min(64, NN - row0);

    #pragma unroll
    for (int i = 0; i < 16; ++i) {
        int f = t + i * 256;
        int k = f >> 6, c = f & 63;
        wc[f] = (c < 32) ? W2[k * 32 + c] : W3[k * 32 + (c - 32)];
    }
    if (t < 64) bc[t] = (t < 32) ? b2[t] : b3[t - 32];
    #pragma unroll
    for (int i = 0; i < 4; ++i) {
        int f = t + i * 256;
        int r = f >> 4, c4 = f & 15;
        float4 v = make_float4(0.f, 0.f, 0.f, 0.f);
        if (r < nrows) v = ((const float4*)(agg + (size_t)(row0 + r) * 64))[c4];
        *(float4*)&as_[r][c4 * 4] = v;
    }
    __syncthreads();

    const int tc = t & 15;
    const int tr = t >> 4;
    float acc[4][4];
    #pragma unroll
    for (int i = 0; i < 4; ++i)
        #pragma unroll
        for (int j = 0; j < 4; ++j) acc[i][j] = 0.f;

    #pragma unroll 4
    for (int k = 0; k < 64; ++k) {
        float4 wv = *(const float4*)&wc[k * 64 + tc * 4];
        #pragma unroll
        for (int i = 0; i < 4; ++i) {
            float xv = as_[tr * 4 + i][k];
            acc[i][0] += xv * wv.x; acc[i][1] += xv * wv.y;
            acc[i][2] += xv * wv.z; acc[i][3] += xv * wv.w;
        }
    }
    const int c0 = tc * 4;
    float4 bias = *(float4*)&bc[c0];
    #pragma unroll
    for (int i = 0; i < 4; ++i) {
        int r = tr * 4 + i;
        if (r < nrows) {
            float4 o = make_float4(acc[i][0] + bias.x, acc[i][1] + bias.y,
                                   acc[i][2] + bias.z, acc[i][3] + bias.w);
            size_t row = (size_t)(row0 + r);
            float* p = (tc < 8) ? (out + row * 32 + c0)
                                : (out + (size_t)NN * 32 + row * 32 + (c0 - 32));
            *(float4*)p = o;
        }
    }
}

extern "C" void kernel_launch(void* const* d_in, const int* in_sizes, int n_in,
                              void* d_out, int out_size, void* d_ws, size_t ws_size,
                              hipStream_t stream) {
    const float* x  = (const float*)d_in[0];
    const int* edges = (const int*)d_in[1];
    const float* W1 = (const float*)d_in[2];
    const float* b1 = (const float*)d_in[3];
    const float* W2 = (const float*)d_in[4];
    const float* b2 = (const float*)d_in[5];
    const float* W3 = (const float*)d_in[6];
    const float* b3 = (const float*)d_in[7];
    float* out = (float*)d_out;

    const int* srcs = edges;            // edges[0]
    const int* dsts = edges + NE;       // edges[1]

    // ws layout (4-byte units)
    int*   cnt     = (int*)d_ws;                    // [NN]
    int*   cursor  = cnt + NN;                      // [NN]
    int*   csr_off = cursor + NN;                   // [NN+1] -> ends 300001
    float* dinv    = (float*)(cnt + 300004);        // [NN]   (pad to %4)
    int*   csr_src = (int*)(cnt + 400004);          // [NE]
    int*   blksum  = cnt + 2000004;                 // [124]
    float* agg     = (float*)(cnt + 2000128);       // [NN*64], 16B aligned

    dim3 blk(256);
    const int gE = (NE + 255) / 256;
    const int gN = (NN + 255) / 256;
    const int gN16 = (NN * 16 + 255) / 256;
    const int gT = (NN + 63) / 64;

    // CSR build (per call; deterministic work)
    hipMemsetAsync(cnt, 0, (size_t)2 * NN * sizeof(int), stream);  // cnt + cursor
    k_count<<<gE, blk, 0, stream>>>(dsts, cnt);
    k_dinvk<<<gN, blk, 0, stream>>>(cnt, dinv);
    k_scan1<<<SCAN_NBLK, blk, 0, stream>>>(cnt, csr_off, blksum);
    k_scan2<<<1, blk, 0, stream>>>(blksum);
    k_scan3<<<gN, blk, 0, stream>>>(csr_off, blksum);
    k_fill<<<gE, blk, 0, stream>>>(srcs, dsts, csr_off, cursor, csr_src);

    // conv1: t1 = x@W1 (into agg), h1 = relu(Agg(t1)+b1) (into out)
    k_gemm1<<<gT, blk, 0, stream>>>(x, W1, agg);
    k_gather<true><<<gN16, blk, 0, stream>>>(csr_off, csr_src, dinv, agg, b1, out);
    // conv2/3 shared aggregation: agg2 = Agg(h1) (into agg), then both GEMMs
    k_gather<false><<<gN16, blk, 0, stream>>>(csr_off, csr_src, dinv, out, b1, agg);
    k_gemm2<<<gT, blk, 0, stream>>>(agg, W2, b2, W3, b3, out);
}

// Round 6
// 292.473 us; speedup vs baseline: 9.4244x; 1.2544x over previous
//
// GCNEncoder MI355X kernel — v3 (two-level counting-sort CSR + pre-scaled gather)
// Resubmission r5: identical to r2/r3/r4 source; prior rounds died to
// UnresponsiveContainer before compile (dead pod lease), never executed.
#include <hip/hip_runtime.h>

#define NN 100000
#define NE 1600000
#define NB 782            // ceil(NN/128) buckets of 128 nodes (bucket = dst >> 7)
#define CHUNK 16384
#define NCHUNK 98         // ceil(NE/CHUNK)

// ---------------- Pass A: coarse histogram (LDS-privatized) ----------------
__global__ __launch_bounds__(256) void k_hist(const int* __restrict__ dst,
                                              int* __restrict__ bhist) {
    __shared__ int lh[NB];
    int t = threadIdx.x;
    for (int i = t; i < NB; i += 256) lh[i] = 0;
    __syncthreads();
    for (int e = blockIdx.x * 256 + t; e < NE; e += 256 * 256)
        atomicAdd(&lh[dst[e] >> 7], 1);
    __syncthreads();
    for (int i = t; i < NB; i += 256)
        if (lh[i]) atomicAdd(&bhist[i], lh[i]);
}

// ---------------- Pass B: scan buckets -> boff, bcursor ----------------
__global__ __launch_bounds__(256) void k_scanb(const int* __restrict__ bhist,
                                               int* __restrict__ boff,
                                               int* __restrict__ bcur) {
    __shared__ int sh[256];
    int t = threadIdx.x;
    int base = t * 4;
    int v0 = (base + 0 < NB) ? bhist[base + 0] : 0;
    int v1 = (base + 1 < NB) ? bhist[base + 1] : 0;
    int v2 = (base + 2 < NB) ? bhist[base + 2] : 0;
    int v3 = (base + 3 < NB) ? bhist[base + 3] : 0;
    int tsum = v0 + v1 + v2 + v3;
    sh[t] = tsum;
    __syncthreads();
    for (int d = 1; d < 256; d <<= 1) {
        int x = (t >= d) ? sh[t - d] : 0;
        __syncthreads();
        sh[t] += x;
        __syncthreads();
    }
    int excl = sh[t] - tsum;
    int p0 = excl, p1 = excl + v0, p2 = excl + v0 + v1, p3 = excl + v0 + v1 + v2;
    if (base + 0 < NB) { boff[base + 0] = p0; bcur[base + 0] = p0; }
    if (base + 1 < NB) { boff[base + 1] = p1; bcur[base + 1] = p1; }
    if (base + 2 < NB) { boff[base + 2] = p2; bcur[base + 2] = p2; }
    if (base + 3 < NB) { boff[base + 3] = p3; bcur[base + 3] = p3; }
    if (t == 255) boff[NB] = sh[255];   // == NE
}

// ---------------- Pass C: chunked scatter into bucket regions ----------------
__global__ __launch_bounds__(256) void k_bscatter(const int* __restrict__ src,
                                                  const int* __restrict__ dst,
                                                  int* __restrict__ bcur,
                                                  int2* __restrict__ pairs) {
    __shared__ int lh[NB];
    __shared__ int lbase[NB];
    int t = threadIdx.x;
    int e0 = blockIdx.x * CHUNK;
    int e1 = min(e0 + CHUNK, NE);
    for (int i = t; i < NB; i += 256) lh[i] = 0;
    __syncthreads();
    for (int e = e0 + t; e < e1; e += 256)
        atomicAdd(&lh[dst[e] >> 7], 1);
    __syncthreads();
    for (int i = t; i < NB; i += 256) {
        int h = lh[i];
        lbase[i] = h ? atomicAdd(&bcur[i], h) : 0;
    }
    __syncthreads();
    for (int i = t; i < NB; i += 256) lh[i] = 0;   // reuse as cursor
    __syncthreads();
    for (int e = e0 + t; e < e1; e += 256) {
        int d = dst[e];
        int b = d >> 7;
        int r = atomicAdd(&lh[b], 1);
        pairs[lbase[b] + r] = make_int2(src[e], d);
    }
}

// ---------------- Pass D: per-bucket fine sort + dinv + csr_off ----------------
__global__ __launch_bounds__(256) void k_fine(const int2* __restrict__ pairs,
                                              const int* __restrict__ boff,
                                              int* __restrict__ csr_off,
                                              int* __restrict__ csr_src,
                                              float* __restrict__ dinv) {
    __shared__ int lcnt[128];
    __shared__ int sc[128];
    __shared__ int lofs[128];
    int t = threadIdx.x;
    int b = blockIdx.x;
    int n0 = b << 7;
    int nnode = min(128, NN - n0);
    int bO = boff[b], bE = boff[b + 1];

    if (t < 128) lcnt[t] = 0;
    __syncthreads();
    for (int e = bO + t; e < bE; e += 256)
        atomicAdd(&lcnt[pairs[e].y - n0], 1);
    __syncthreads();
    if (t < 128) sc[t] = lcnt[t];
    __syncthreads();
    for (int d = 1; d < 128; d <<= 1) {
        int x = (t >= d && t < 128) ? sc[t - d] : 0;
        __syncthreads();
        if (t < 128) sc[t] += x;
        __syncthreads();
    }
    if (t < 128) {
        int excl = sc[t] - lcnt[t];
        lofs[t] = excl;
        if (t < nnode) {
            int n = n0 + t;
            csr_off[n] = bO + excl;
            dinv[n] = rsqrtf(1.0f + (float)lcnt[t]);
        }
        lcnt[t] = 0;   // reuse as cursor
    }
    if (b == NB - 1 && t == 0) csr_off[NN] = NE;
    __syncthreads();
    for (int e = bO + t; e < bE; e += 256) {
        int2 p = pairs[e];
        int li = p.y - n0;
        int r = atomicAdd(&lcnt[li], 1);
        csr_src[bO + lofs[li] + r] = p.x;
    }
}

// ---------------- GEMM1: t1' = dinv * (x @ W1)   [NN,128]x[128,64] ----------------
__global__ __launch_bounds__(256) void k_gemm1(const float* __restrict__ x,
                                               const float* __restrict__ W1,
                                               const float* __restrict__ dinv,
                                               float* __restrict__ t1) {
    __shared__ float xs[64][132];
    __shared__ float ws[128 * 64];
    const int t = threadIdx.x;
    const int row0 = blockIdx.x * 64;
    const int nrows = min(64, NN - row0);

    #pragma unroll
    for (int i = 0; i < 8; ++i) {
        int f = t + i * 256;
        *(float4*)&ws[f * 4] = ((const float4*)W1)[f];
    }
    #pragma unroll
    for (int i = 0; i < 8; ++i) {
        int f = t + i * 256;
        int r = f >> 5, k4 = f & 31;
        float4 v = make_float4(0.f, 0.f, 0.f, 0.f);
        if (r < nrows) v = ((const float4*)(x + (size_t)(row0 + r) * 128))[k4];
        *(float4*)&xs[r][k4 * 4] = v;
    }
    __syncthreads();

    const int tc = t & 15;
    const int tr = t >> 4;
    float acc[4][4];
    #pragma unroll
    for (int i = 0; i < 4; ++i)
        #pragma unroll
        for (int j = 0; j < 4; ++j) acc[i][j] = 0.f;

    #pragma unroll 4
    for (int k = 0; k < 128; ++k) {
        float4 wv = *(const float4*)&ws[k * 64 + tc * 4];
        #pragma unroll
        for (int i = 0; i < 4; ++i) {
            float xv = xs[tr * 4 + i][k];
            acc[i][0] += xv * wv.x; acc[i][1] += xv * wv.y;
            acc[i][2] += xv * wv.z; acc[i][3] += xv * wv.w;
        }
    }
    #pragma unroll
    for (int i = 0; i < 4; ++i) {
        int r = tr * 4 + i;
        if (r < nrows) {
            float dn = dinv[row0 + r];
            float4 o = make_float4(acc[i][0] * dn, acc[i][1] * dn,
                                   acc[i][2] * dn, acc[i][3] * dn);
            *(float4*)&t1[(size_t)(row0 + r) * 64 + tc * 4] = o;
        }
    }
}

// ---------------- gather aggregation (pre-scaled h') ----------------
// input h' where h'[n] = dinv[n]*h[n].  acc = h'[n] + sum_{e:dst=n} h'[src].
// RELU variant (layer1): out = dinv[n] * relu(dinv[n]*acc + b)   (pre-scaled for next layer)
// else    (layer2/3):    out = dinv[n] * acc
template <bool RELU>
__global__ __launch_bounds__(256) void k_gather(const int* __restrict__ off,
                                                const int* __restrict__ csr,
                                                const float* __restrict__ dinv,
                                                const float* __restrict__ hp,
                                                const float* __restrict__ bias,
                                                float* __restrict__ outp) {
    int idx = blockIdx.x * 256 + threadIdx.x;   // 16 lanes per node
    int n = idx >> 4;
    if (n >= NN) return;
    int c4 = idx & 15;
    float dn = dinv[n];
    const float4* h4 = (const float4*)hp;
    float4 acc = h4[(size_t)n * 16 + c4];       // self term
    int b = off[n], e = off[n + 1];
    int i = b;
    if (i < e) {
        int s = csr[i];
        for (++i; i < e; ++i) {
            int sn = csr[i];                     // prefetch next index
            float4 v = h4[(size_t)s * 16 + c4];
            acc.x += v.x; acc.y += v.y; acc.z += v.z; acc.w += v.w;
            s = sn;
        }
        float4 v = h4[(size_t)s * 16 + c4];
        acc.x += v.x; acc.y += v.y; acc.z += v.z; acc.w += v.w;
    }
    float4 o;
    if (RELU) {
        float4 bv = ((const float4*)bias)[c4];
        o.x = dn * fmaxf(dn * acc.x + bv.x, 0.f);
        o.y = dn * fmaxf(dn * acc.y + bv.y, 0.f);
        o.z = dn * fmaxf(dn * acc.z + bv.z, 0.f);
        o.w = dn * fmaxf(dn * acc.w + bv.w, 0.f);
    } else {
        o.x = dn * acc.x; o.y = dn * acc.y; o.z = dn * acc.z; o.w = dn * acc.w;
    }
    ((float4*)outp)[idx] = o;
}

// ---------------- GEMM2: out1 = agg@W2+b2, out2 = agg@W3+b3 ----------------
__global__ __launch_bounds__(256) void k_gemm2(const float* __restrict__ agg,
                                               const float* __restrict__ W2, const float* __restrict__ b2,
                                               const float* __restrict__ W3, const float* __restrict__ b3,
                                               float* __restrict__ out) {
    __shared__ float as_[64][68];
    __shared__ float wc[64 * 64];
    __shared__ float bc[64];
    const int t = threadIdx.x;
    const int row0 = blockIdx.x * 64;
    const int nrows = min(64, NN - row0);

    #pragma unroll
    for (int i = 0; i < 16; ++i) {
        int f = t + i * 256;
        int k = f >> 6, c = f & 63;
        wc[f] = (c < 32) ? W2[k * 32 + c] : W3[k * 32 + (c - 32)];
    }
    if (t < 64) bc[t] = (t < 32) ? b2[t] : b3[t - 32];
    #pragma unroll
    for (int i = 0; i < 4; ++i) {
        int f = t + i * 256;
        int r = f >> 4, c4 = f & 15;
        float4 v = make_float4(0.f, 0.f, 0.f, 0.f);
        if (r < nrows) v = ((const float4*)(agg + (size_t)(row0 + r) * 64))[c4];
        *(float4*)&as_[r][c4 * 4] = v;
    }
    __syncthreads();

    const int tc = t & 15;
    const int tr = t >> 4;
    float acc[4][4];
    #pragma unroll
    for (int i = 0; i < 4; ++i)
        #pragma unroll
        for (int j = 0; j < 4; ++j) acc[i][j] = 0.f;

    #pragma unroll 4
    for (int k = 0; k < 64; ++k) {
        float4 wv = *(const float4*)&wc[k * 64 + tc * 4];
        #pragma unroll
        for (int i = 0; i < 4; ++i) {
            float xv = as_[tr * 4 + i][k];
            acc[i][0] += xv * wv.x; acc[i][1] += xv * wv.y;
            acc[i][2] += xv * wv.z; acc[i][3] += xv * wv.w;
        }
    }
    const int c0 = tc * 4;
    float4 bias = *(float4*)&bc[c0];
    #pragma unroll
    for (int i = 0; i < 4; ++i) {
        int r = tr * 4 + i;
        if (r < nrows) {
            float4 o = make_float4(acc[i][0] + bias.x, acc[i][1] + bias.y,
                                   acc[i][2] + bias.z, acc[i][3] + bias.w);
            size_t row = (size_t)(row0 + r);
            float* p = (tc < 8) ? (out + row * 32 + c0)
                                : (out + (size_t)NN * 32 + row * 32 + (c0 - 32));
            *(float4*)p = o;
        }
    }
}

extern "C" void kernel_launch(void* const* d_in, const int* in_sizes, int n_in,
                              void* d_out, int out_size, void* d_ws, size_t ws_size,
                              hipStream_t stream) {
    const float* x  = (const float*)d_in[0];
    const int* edges = (const int*)d_in[1];
    const float* W1 = (const float*)d_in[2];
    const float* b1 = (const float*)d_in[3];
    const float* W2 = (const float*)d_in[4];
    const float* b2 = (const float*)d_in[5];
    const float* W3 = (const float*)d_in[6];
    const float* b3 = (const float*)d_in[7];
    float* out = (float*)d_out;

    const int* srcs = edges;            // edges[0]
    const int* dsts = edges + NE;       // edges[1]

    // ws layout (4-byte units)
    int*   csr_off = (int*)d_ws;                    // [NN+1]           0 .. 100000
    float* dinv    = (float*)((int*)d_ws + 100004); // [NN]
    int*   csr_src = (int*)d_ws + 200004;           // [NE]
    int*   bhist   = (int*)d_ws + 1800004;          // [NB]
    int*   boff    = (int*)d_ws + 1800788;          // [NB+1]
    int*   bcur    = (int*)d_ws + 1801572;          // [NB]
    float* agg     = (float*)((int*)d_ws + 1802356);// [NN*64], 16B aligned
    int2*  pairs   = (int2*)agg;                    // [NE] int2 (overlaps agg; done before agg is written)

    dim3 blk(256);
    const int gN16 = (NN * 16 + 255) / 256;
    const int gT = (NN + 63) / 64;

    // CSR build: two-level counting sort
    hipMemsetAsync(bhist, 0, NB * sizeof(int), stream);
    k_hist<<<256, blk, 0, stream>>>(dsts, bhist);
    k_scanb<<<1, blk, 0, stream>>>(bhist, boff, bcur);
    k_bscatter<<<NCHUNK, blk, 0, stream>>>(srcs, dsts, bcur, pairs);
    k_fine<<<NB, blk, 0, stream>>>(pairs, boff, csr_off, csr_src, dinv);

    // conv1: t1' = dinv*(x@W1) (into agg), h1' = dinv*relu(Agg+b1) (into out)
    k_gemm1<<<gT, blk, 0, stream>>>(x, W1, dinv, agg);
    k_gather<true><<<gN16, blk, 0, stream>>>(csr_off, csr_src, dinv, agg, b1, out);
    // conv2/3 shared aggregation: agg2 = Agg(h1) (into agg), then both GEMMs
    k_gather<false><<<gN16, blk, 0, stream>>>(csr_off, csr_src, dinv, out, b1, agg);
    k_gemm2<<<gT, blk, 0, stream>>>(agg, W2, b2, W3, b3, out);
}

// Round 7
// 247.660 us; speedup vs baseline: 11.1297x; 1.1809x over previous
//
// GCNEncoder MI355X kernel — v4: bf16-compressed gather features
// (two-level counting-sort CSR + 8-lane/node bf16 gather + fp32 accum)
#include <hip/hip_runtime.h>

#define NN 100000
#define NE 1600000
#define NB 782            // ceil(NN/128) buckets of 128 nodes (bucket = dst >> 7)
#define CHUNK 16384
#define NCHUNK 98         // ceil(NE/CHUNK)

// ---- bf16 helpers (RNE pack, bit-op unpack) ----
__device__ inline unsigned short f2bf(float f) {
    unsigned int u = __float_as_uint(f);
    unsigned int r = u + 0x7fffu + ((u >> 16) & 1u);
    return (unsigned short)(r >> 16);
}
__device__ inline float bf_lo(unsigned int u) { return __uint_as_float(u << 16); }
__device__ inline float bf_hi(unsigned int u) { return __uint_as_float(u & 0xffff0000u); }

// ---------------- Pass A: coarse histogram (LDS-privatized) ----------------
__global__ __launch_bounds__(256) void k_hist(const int* __restrict__ dst,
                                              int* __restrict__ bhist) {
    __shared__ int lh[NB];
    int t = threadIdx.x;
    for (int i = t; i < NB; i += 256) lh[i] = 0;
    __syncthreads();
    for (int e = blockIdx.x * 256 + t; e < NE; e += 256 * 256)
        atomicAdd(&lh[dst[e] >> 7], 1);
    __syncthreads();
    for (int i = t; i < NB; i += 256)
        if (lh[i]) atomicAdd(&bhist[i], lh[i]);
}

// ---------------- Pass B: scan buckets -> boff, bcursor ----------------
__global__ __launch_bounds__(256) void k_scanb(const int* __restrict__ bhist,
                                               int* __restrict__ boff,
                                               int* __restrict__ bcur) {
    __shared__ int sh[256];
    int t = threadIdx.x;
    int base = t * 4;
    int v0 = (base + 0 < NB) ? bhist[base + 0] : 0;
    int v1 = (base + 1 < NB) ? bhist[base + 1] : 0;
    int v2 = (base + 2 < NB) ? bhist[base + 2] : 0;
    int v3 = (base + 3 < NB) ? bhist[base + 3] : 0;
    int tsum = v0 + v1 + v2 + v3;
    sh[t] = tsum;
    __syncthreads();
    for (int d = 1; d < 256; d <<= 1) {
        int x = (t >= d) ? sh[t - d] : 0;
        __syncthreads();
        sh[t] += x;
        __syncthreads();
    }
    int excl = sh[t] - tsum;
    int p0 = excl, p1 = excl + v0, p2 = excl + v0 + v1, p3 = excl + v0 + v1 + v2;
    if (base + 0 < NB) { boff[base + 0] = p0; bcur[base + 0] = p0; }
    if (base + 1 < NB) { boff[base + 1] = p1; bcur[base + 1] = p1; }
    if (base + 2 < NB) { boff[base + 2] = p2; bcur[base + 2] = p2; }
    if (base + 3 < NB) { boff[base + 3] = p3; bcur[base + 3] = p3; }
    if (t == 255) boff[NB] = sh[255];   // == NE
}

// ---------------- Pass C: chunked scatter into bucket regions ----------------
__global__ __launch_bounds__(256) void k_bscatter(const int* __restrict__ src,
                                                  const int* __restrict__ dst,
                                                  int* __restrict__ bcur,
                                                  int2* __restrict__ pairs) {
    __shared__ int lh[NB];
    __shared__ int lbase[NB];
    int t = threadIdx.x;
    int e0 = blockIdx.x * CHUNK;
    int e1 = min(e0 + CHUNK, NE);
    for (int i = t; i < NB; i += 256) lh[i] = 0;
    __syncthreads();
    for (int e = e0 + t; e < e1; e += 256)
        atomicAdd(&lh[dst[e] >> 7], 1);
    __syncthreads();
    for (int i = t; i < NB; i += 256) {
        int h = lh[i];
        lbase[i] = h ? atomicAdd(&bcur[i], h) : 0;
    }
    __syncthreads();
    for (int i = t; i < NB; i += 256) lh[i] = 0;   // reuse as cursor
    __syncthreads();
    for (int e = e0 + t; e < e1; e += 256) {
        int d = dst[e];
        int b = d >> 7;
        int r = atomicAdd(&lh[b], 1);
        pairs[lbase[b] + r] = make_int2(src[e], d);
    }
}

// ---------------- Pass D: per-bucket fine sort + dinv + csr_off ----------------
__global__ __launch_bounds__(256) void k_fine(const int2* __restrict__ pairs,
                                              const int* __restrict__ boff,
                                              int* __restrict__ csr_off,
                                              int* __restrict__ csr_src,
                                              float* __restrict__ dinv) {
    __shared__ int lcnt[128];
    __shared__ int sc[128];
    __shared__ int lofs[128];
    int t = threadIdx.x;
    int b = blockIdx.x;
    int n0 = b << 7;
    int nnode = min(128, NN - n0);
    int bO = boff[b], bE = boff[b + 1];

    if (t < 128) lcnt[t] = 0;
    __syncthreads();
    for (int e = bO + t; e < bE; e += 256)
        atomicAdd(&lcnt[pairs[e].y - n0], 1);
    __syncthreads();
    if (t < 128) sc[t] = lcnt[t];
    __syncthreads();
    for (int d = 1; d < 128; d <<= 1) {
        int x = (t >= d && t < 128) ? sc[t - d] : 0;
        __syncthreads();
        if (t < 128) sc[t] += x;
        __syncthreads();
    }
    if (t < 128) {
        int excl = sc[t] - lcnt[t];
        lofs[t] = excl;
        if (t < nnode) {
            int n = n0 + t;
            csr_off[n] = bO + excl;
            dinv[n] = rsqrtf(1.0f + (float)lcnt[t]);
        }
        lcnt[t] = 0;   // reuse as cursor
    }
    if (b == NB - 1 && t == 0) csr_off[NN] = NE;
    __syncthreads();
    for (int e = bO + t; e < bE; e += 256) {
        int2 p = pairs[e];
        int li = p.y - n0;
        int r = atomicAdd(&lcnt[li], 1);
        csr_src[bO + lofs[li] + r] = p.x;
    }
}

// ---------------- GEMM1: t1b = bf16( dinv * (x @ W1) )  [NN,128]x[128,64] ----------------
__global__ __launch_bounds__(256) void k_gemm1(const float* __restrict__ x,
                                               const float* __restrict__ W1,
                                               const float* __restrict__ dinv,
                                               unsigned short* __restrict__ t1b) {
    __shared__ float xs[64][132];
    __shared__ float ws[128 * 64];
    const int t = threadIdx.x;
    const int row0 = blockIdx.x * 64;
    const int nrows = min(64, NN - row0);

    #pragma unroll
    for (int i = 0; i < 8; ++i) {
        int f = t + i * 256;
        *(float4*)&ws[f * 4] = ((const float4*)W1)[f];
    }
    #pragma unroll
    for (int i = 0; i < 8; ++i) {
        int f = t + i * 256;
        int r = f >> 5, k4 = f & 31;
        float4 v = make_float4(0.f, 0.f, 0.f, 0.f);
        if (r < nrows) v = ((const float4*)(x + (size_t)(row0 + r) * 128))[k4];
        *(float4*)&xs[r][k4 * 4] = v;
    }
    __syncthreads();

    const int tc = t & 15;
    const int tr = t >> 4;
    float acc[4][4];
    #pragma unroll
    for (int i = 0; i < 4; ++i)
        #pragma unroll
        for (int j = 0; j < 4; ++j) acc[i][j] = 0.f;

    #pragma unroll 4
    for (int k = 0; k < 128; ++k) {
        float4 wv = *(const float4*)&ws[k * 64 + tc * 4];
        #pragma unroll
        for (int i = 0; i < 4; ++i) {
            float xv = xs[tr * 4 + i][k];
            acc[i][0] += xv * wv.x; acc[i][1] += xv * wv.y;
            acc[i][2] += xv * wv.z; acc[i][3] += xv * wv.w;
        }
    }
    #pragma unroll
    for (int i = 0; i < 4; ++i) {
        int r = tr * 4 + i;
        if (r < nrows) {
            float dn = dinv[row0 + r];
            ushort4 o;
            o.x = f2bf(acc[i][0] * dn); o.y = f2bf(acc[i][1] * dn);
            o.z = f2bf(acc[i][2] * dn); o.w = f2bf(acc[i][3] * dn);
            *(ushort4*)&t1b[(size_t)(row0 + r) * 64 + tc * 4] = o;
        }
    }
}

// ---------------- bf16 gather aggregation (8 lanes/node, 8 ch/lane) ----------------
// input hb' (bf16) where h'[n] = dinv[n]*h[n].  acc = h'[n] + sum_{e:dst=n} h'[src].
// RELU (layer1): out = bf16( dinv[n] * relu(dinv[n]*acc + b) )  (pre-scaled for next layer)
// else (layer2/3): out = bf16( dinv[n] * acc )
template <bool RELU>
__global__ __launch_bounds__(256) void k_gather8(const int* __restrict__ off,
                                                 const int* __restrict__ csr,
                                                 const float* __restrict__ dinv,
                                                 const unsigned short* __restrict__ hb,
                                                 const float* __restrict__ bias,
                                                 unsigned int* __restrict__ outp) {
    int idx = blockIdx.x * 256 + threadIdx.x;   // 8 lanes per node
    int n = idx >> 3;
    if (n >= NN) return;
    int c8 = idx & 7;                           // channels c8*8 .. c8*8+7
    const uint4* h4 = (const uint4*)hb;         // row stride = 8 uint4 (64 bf16)
    float dn = dinv[n];
    float acc[8];
    {
        uint4 v = h4[(size_t)n * 8 + c8];       // self term
        acc[0] = bf_lo(v.x); acc[1] = bf_hi(v.x);
        acc[2] = bf_lo(v.y); acc[3] = bf_hi(v.y);
        acc[4] = bf_lo(v.z); acc[5] = bf_hi(v.z);
        acc[6] = bf_lo(v.w); acc[7] = bf_hi(v.w);
    }
    int b = off[n], e = off[n + 1];
    int i = b;
    if (i < e) {
        int s = csr[i];
        for (++i; i < e; ++i) {
            int sn = csr[i];                    // prefetch next index
            uint4 v = h4[(size_t)s * 8 + c8];
            acc[0] += bf_lo(v.x); acc[1] += bf_hi(v.x);
            acc[2] += bf_lo(v.y); acc[3] += bf_hi(v.y);
            acc[4] += bf_lo(v.z); acc[5] += bf_hi(v.z);
            acc[6] += bf_lo(v.w); acc[7] += bf_hi(v.w);
            s = sn;
        }
        uint4 v = h4[(size_t)s * 8 + c8];
        acc[0] += bf_lo(v.x); acc[1] += bf_hi(v.x);
        acc[2] += bf_lo(v.y); acc[3] += bf_hi(v.y);
        acc[4] += bf_lo(v.z); acc[5] += bf_hi(v.z);
        acc[6] += bf_lo(v.w); acc[7] += bf_hi(v.w);
    }
    float o[8];
    if (RELU) {
        float4 b0 = ((const float4*)bias)[c8 * 2];
        float4 b1 = ((const float4*)bias)[c8 * 2 + 1];
        o[0] = dn * fmaxf(dn * acc[0] + b0.x, 0.f);
        o[1] = dn * fmaxf(dn * acc[1] + b0.y, 0.f);
        o[2] = dn * fmaxf(dn * acc[2] + b0.z, 0.f);
        o[3] = dn * fmaxf(dn * acc[3] + b0.w, 0.f);
        o[4] = dn * fmaxf(dn * acc[4] + b1.x, 0.f);
        o[5] = dn * fmaxf(dn * acc[5] + b1.y, 0.f);
        o[6] = dn * fmaxf(dn * acc[6] + b1.z, 0.f);
        o[7] = dn * fmaxf(dn * acc[7] + b1.w, 0.f);
    } else {
        #pragma unroll
        for (int j = 0; j < 8; ++j) o[j] = dn * acc[j];
    }
    uint4 p;
    p.x = (unsigned int)f2bf(o[0]) | ((unsigned int)f2bf(o[1]) << 16);
    p.y = (unsigned int)f2bf(o[2]) | ((unsigned int)f2bf(o[3]) << 16);
    p.z = (unsigned int)f2bf(o[4]) | ((unsigned int)f2bf(o[5]) << 16);
    p.w = (unsigned int)f2bf(o[6]) | ((unsigned int)f2bf(o[7]) << 16);
    ((uint4*)outp)[(size_t)n * 8 + c8] = p;
}

// ---------------- GEMM2: out1 = agg@W2+b2, out2 = agg@W3+b3 (agg in bf16) ----------------
__global__ __launch_bounds__(256) void k_gemm2(const unsigned short* __restrict__ aggb,
                                               const float* __restrict__ W2, const float* __restrict__ b2,
                                               const float* __restrict__ W3, const float* __restrict__ b3,
                                               float* __restrict__ out) {
    __shared__ float as_[64][72];     // +8 pad
    __shared__ float wc[64 * 64];
    __shared__ float bc[64];
    const int t = threadIdx.x;
    const int row0 = blockIdx.x * 64;
    const int nrows = min(64, NN - row0);

    #pragma unroll
    for (int i = 0; i < 16; ++i) {
        int f = t + i * 256;
        int k = f >> 6, c = f & 63;
        wc[f] = (c < 32) ? W2[k * 32 + c] : W3[k * 32 + (c - 32)];
    }
    if (t < 64) bc[t] = (t < 32) ? b2[t] : b3[t - 32];
    // stage agg tile: 64 rows x 64 bf16 = 512 uint4
    #pragma unroll
    for (int i = 0; i < 2; ++i) {
        int f = t + i * 256;           // 0..511
        int r = f >> 3, c8 = f & 7;
        uint4 v = make_uint4(0u, 0u, 0u, 0u);
        if (r < nrows) v = ((const uint4*)(aggb + (size_t)(row0 + r) * 64))[c8];
        float* dp = &as_[r][c8 * 8];
        dp[0] = bf_lo(v.x); dp[1] = bf_hi(v.x);
        dp[2] = bf_lo(v.y); dp[3] = bf_hi(v.y);
        dp[4] = bf_lo(v.z); dp[5] = bf_hi(v.z);
        dp[6] = bf_lo(v.w); dp[7] = bf_hi(v.w);
    }
    __syncthreads();

    const int tc = t & 15;
    const int tr = t >> 4;
    float acc[4][4];
    #pragma unroll
    for (int i = 0; i < 4; ++i)
        #pragma unroll
        for (int j = 0; j < 4; ++j) acc[i][j] = 0.f;

    #pragma unroll 4
    for (int k = 0; k < 64; ++k) {
        float4 wv = *(const float4*)&wc[k * 64 + tc * 4];
        #pragma unroll
        for (int i = 0; i < 4; ++i) {
            float xv = as_[tr * 4 + i][k];
            acc[i][0] += xv * wv.x; acc[i][1] += xv * wv.y;
            acc[i][2] += xv * wv.z; acc[i][3] += xv * wv.w;
        }
    }
    const int c0 = tc * 4;
    float4 bias = *(float4*)&bc[c0];
    #pragma unroll
    for (int i = 0; i < 4; ++i) {
        int r = tr * 4 + i;
        if (r < nrows) {
            float4 o = make_float4(acc[i][0] + bias.x, acc[i][1] + bias.y,
                                   acc[i][2] + bias.z, acc[i][3] + bias.w);
            size_t row = (size_t)(row0 + r);
            float* p = (tc < 8) ? (out + row * 32 + c0)
                                : (out + (size_t)NN * 32 + row * 32 + (c0 - 32));
            *(float4*)p = o;
        }
    }
}

extern "C" void kernel_launch(void* const* d_in, const int* in_sizes, int n_in,
                              void* d_out, int out_size, void* d_ws, size_t ws_size,
                              hipStream_t stream) {
    const float* x  = (const float*)d_in[0];
    const int* edges = (const int*)d_in[1];
    const float* W1 = (const float*)d_in[2];
    const float* b1 = (const float*)d_in[3];
    const float* W2 = (const float*)d_in[4];
    const float* b2 = (const float*)d_in[5];
    const float* W3 = (const float*)d_in[6];
    const float* b3 = (const float*)d_in[7];
    float* out = (float*)d_out;

    const int* srcs = edges;            // edges[0]
    const int* dsts = edges + NE;       // edges[1]

    // ws layout (4-byte words), total 8,202,356 words = 32.8 MB
    int*   csr_off = (int*)d_ws;                    // [NN+1]
    float* dinv    = (float*)((int*)d_ws + 100004); // [NN]
    int*   csr_src = (int*)d_ws + 200004;           // [NE]
    int*   bhist   = (int*)d_ws + 1800004;          // [NB]
    int*   boff    = (int*)d_ws + 1800788;          // [NB+1]
    int*   bcur    = (int*)d_ws + 1801572;          // [NB]
    // region A: pairs [NE int2] = 3.2e6 words; reused as t1b, then as aggb
    int2*  pairs   = (int2*)((int*)d_ws + 1802356);
    unsigned short* t1b  = (unsigned short*)pairs;          // [NN*64] bf16 (12.8 MB)
    unsigned short* aggb = (unsigned short*)pairs;          // [NN*64] bf16 (t1b dead by then)
    // region B: h1b [NN*64] bf16
    unsigned short* h1b  = (unsigned short*)((int*)d_ws + 5002356);

    dim3 blk(256);
    const int gN8 = (NN * 8 + 255) / 256;   // 3125
    const int gT = (NN + 63) / 64;

    // CSR build: two-level counting sort
    hipMemsetAsync(bhist, 0, NB * sizeof(int), stream);
    k_hist<<<256, blk, 0, stream>>>(dsts, bhist);
    k_scanb<<<1, blk, 0, stream>>>(bhist, boff, bcur);
    k_bscatter<<<NCHUNK, blk, 0, stream>>>(srcs, dsts, bcur, pairs);
    k_fine<<<NB, blk, 0, stream>>>(pairs, boff, csr_off, csr_src, dinv);

    // conv1: t1b = bf16(dinv*(x@W1)); h1b = bf16(dinv*relu(Agg(t1)+b1))
    k_gemm1<<<gT, blk, 0, stream>>>(x, W1, dinv, t1b);
    k_gather8<true><<<gN8, blk, 0, stream>>>(csr_off, csr_src, dinv, t1b, b1,
                                             (unsigned int*)h1b);
    // conv2/3 shared aggregation: aggb = bf16(Agg(h1)), then both GEMMs
    k_gather8<false><<<gN8, blk, 0, stream>>>(csr_off, csr_src, dinv, h1b, b1,
                                              (unsigned int*)aggb);
    k_gemm2<<<gT, blk, 0, stream>>>(aggb, W2, b2, W3, b3, out);
}

// Round 8
// 180.376 us; speedup vs baseline: 15.2813x; 1.3730x over previous
//
// GCNEncoder MI355X kernel — v5: rebalanced 2-level sort (NB=391, packed 4B pairs,
// 512-thr bscatter) + bf16-compressed 8-lane gather
#include <hip/hip_runtime.h>

#define NN 100000
#define NE 1600000
#define NB 391            // ceil(NN/256) buckets of 256 nodes (bucket = dst >> 8)
#define CHUNK 4096
#define NCHUNK 391        // ceil(NE/CHUNK)

// ---- bf16 helpers (RNE pack, bit-op unpack) ----
__device__ inline unsigned short f2bf(float f) {
    unsigned int u = __float_as_uint(f);
    unsigned int r = u + 0x7fffu + ((u >> 16) & 1u);
    return (unsigned short)(r >> 16);
}
__device__ inline float bf_lo(unsigned int u) { return __uint_as_float(u << 16); }
__device__ inline float bf_hi(unsigned int u) { return __uint_as_float(u & 0xffff0000u); }

// ---------------- Pass A: coarse histogram (LDS-privatized) ----------------
__global__ __launch_bounds__(256) void k_hist(const int* __restrict__ dst,
                                              int* __restrict__ bhist) {
    __shared__ int lh[NB];
    int t = threadIdx.x;
    for (int i = t; i < NB; i += 256) lh[i] = 0;
    __syncthreads();
    for (int e = blockIdx.x * 256 + t; e < NE; e += 256 * 256)
        atomicAdd(&lh[dst[e] >> 8], 1);
    __syncthreads();
    for (int i = t; i < NB; i += 256)
        if (lh[i]) atomicAdd(&bhist[i], lh[i]);
}

// ---------------- Pass B: scan buckets -> boff, bcursor ----------------
__global__ __launch_bounds__(256) void k_scanb(const int* __restrict__ bhist,
                                               int* __restrict__ boff,
                                               int* __restrict__ bcur) {
    __shared__ int sh[256];
    int t = threadIdx.x;
    int base = t * 2;
    int v0 = (base + 0 < NB) ? bhist[base + 0] : 0;
    int v1 = (base + 1 < NB) ? bhist[base + 1] : 0;
    int tsum = v0 + v1;
    sh[t] = tsum;
    __syncthreads();
    for (int d = 1; d < 256; d <<= 1) {
        int x = (t >= d) ? sh[t - d] : 0;
        __syncthreads();
        sh[t] += x;
        __syncthreads();
    }
    int excl = sh[t] - tsum;
    if (base + 0 < NB) { boff[base + 0] = excl;      bcur[base + 0] = excl; }
    if (base + 1 < NB) { boff[base + 1] = excl + v0; bcur[base + 1] = excl + v0; }
    if (t == 255) boff[NB] = sh[255];   // == NE
}

// ---------------- Pass C: chunked scatter into bucket regions (packed 4B) ----------------
// packed word = src (17 bits) | local_dst (8 bits) << 17
__global__ __launch_bounds__(512) void k_bscatter(const int* __restrict__ src,
                                                  const int* __restrict__ dst,
                                                  int* __restrict__ bcur,
                                                  unsigned int* __restrict__ pairs) {
    __shared__ int lh[NB];
    __shared__ int lbase[NB];
    int t = threadIdx.x;
    int e0 = blockIdx.x * CHUNK;
    int e1 = min(e0 + CHUNK, NE);
    for (int i = t; i < NB; i += 512) lh[i] = 0;
    __syncthreads();
    for (int e = e0 + t; e < e1; e += 512)
        atomicAdd(&lh[dst[e] >> 8], 1);
    __syncthreads();
    int rot = (int)((blockIdx.x * 97u) % NB);      // stagger global-atomic bursts
    for (int i = t; i < NB; i += 512) {
        int ii = i + rot; if (ii >= NB) ii -= NB;
        int h = lh[ii];
        lbase[ii] = h ? atomicAdd(&bcur[ii], h) : 0;
    }
    __syncthreads();
    for (int i = t; i < NB; i += 512) lh[i] = 0;   // reuse as cursor
    __syncthreads();
    for (int e = e0 + t; e < e1; e += 512) {
        int d = dst[e];
        int b = d >> 8;
        int r = atomicAdd(&lh[b], 1);
        pairs[lbase[b] + r] = (unsigned int)src[e] | ((unsigned int)(d & 255) << 17);
    }
}

// ---------------- Pass D: per-bucket fine sort + dinv + csr_off ----------------
__global__ __launch_bounds__(256) void k_fine(const unsigned int* __restrict__ pairs,
                                              const int* __restrict__ boff,
                                              int* __restrict__ csr_off,
                                              int* __restrict__ csr_src,
                                              float* __restrict__ dinv) {
    __shared__ int lcnt[256];
    __shared__ int sc[256];
    __shared__ int lofs[256];
    int t = threadIdx.x;
    int b = blockIdx.x;
    int n0 = b << 8;
    int nnode = min(256, NN - n0);
    int bO = boff[b], bE = boff[b + 1];

    lcnt[t] = 0;
    __syncthreads();
    for (int e = bO + t; e < bE; e += 256)
        atomicAdd(&lcnt[pairs[e] >> 17], 1);
    __syncthreads();
    sc[t] = lcnt[t];
    __syncthreads();
    for (int d = 1; d < 256; d <<= 1) {
        int x = (t >= d) ? sc[t - d] : 0;
        __syncthreads();
        sc[t] += x;
        __syncthreads();
    }
    {
        int excl = sc[t] - lcnt[t];
        lofs[t] = excl;
        if (t < nnode) {
            int n = n0 + t;
            csr_off[n] = bO + excl;
            dinv[n] = rsqrtf(1.0f + (float)lcnt[t]);
        }
        lcnt[t] = 0;   // reuse as cursor
    }
    if (b == NB - 1 && t == 0) csr_off[NN] = NE;
    __syncthreads();
    for (int e = bO + t; e < bE; e += 256) {
        unsigned int w = pairs[e];
        int li = (int)(w >> 17);
        int r = atomicAdd(&lcnt[li], 1);
        csr_src[bO + lofs[li] + r] = (int)(w & 0x1FFFFu);
    }
}

// ---------------- GEMM1: t1b = bf16( dinv * (x @ W1) )  [NN,128]x[128,64] ----------------
__global__ __launch_bounds__(256) void k_gemm1(const float* __restrict__ x,
                                               const float* __restrict__ W1,
                                               const float* __restrict__ dinv,
                                               unsigned short* __restrict__ t1b) {
    __shared__ float xs[64][132];
    __shared__ float ws[128 * 64];
    const int t = threadIdx.x;
    const int row0 = blockIdx.x * 64;
    const int nrows = min(64, NN - row0);

    #pragma unroll
    for (int i = 0; i < 8; ++i) {
        int f = t + i * 256;
        *(float4*)&ws[f * 4] = ((const float4*)W1)[f];
    }
    #pragma unroll
    for (int i = 0; i < 8; ++i) {
        int f = t + i * 256;
        int r = f >> 5, k4 = f & 31;
        float4 v = make_float4(0.f, 0.f, 0.f, 0.f);
        if (r < nrows) v = ((const float4*)(x + (size_t)(row0 + r) * 128))[k4];
        *(float4*)&xs[r][k4 * 4] = v;
    }
    __syncthreads();

    const int tc = t & 15;
    const int tr = t >> 4;
    float acc[4][4];
    #pragma unroll
    for (int i = 0; i < 4; ++i)
        #pragma unroll
        for (int j = 0; j < 4; ++j) acc[i][j] = 0.f;

    #pragma unroll 4
    for (int k = 0; k < 128; ++k) {
        float4 wv = *(const float4*)&ws[k * 64 + tc * 4];
        #pragma unroll
        for (int i = 0; i < 4; ++i) {
            float xv = xs[tr * 4 + i][k];
            acc[i][0] += xv * wv.x; acc[i][1] += xv * wv.y;
            acc[i][2] += xv * wv.z; acc[i][3] += xv * wv.w;
        }
    }
    #pragma unroll
    for (int i = 0; i < 4; ++i) {
        int r = tr * 4 + i;
        if (r < nrows) {
            float dn = dinv[row0 + r];
            ushort4 o;
            o.x = f2bf(acc[i][0] * dn); o.y = f2bf(acc[i][1] * dn);
            o.z = f2bf(acc[i][2] * dn); o.w = f2bf(acc[i][3] * dn);
            *(ushort4*)&t1b[(size_t)(row0 + r) * 64 + tc * 4] = o;
        }
    }
}

// ---------------- bf16 gather aggregation (8 lanes/node, 8 ch/lane) ----------------
template <bool RELU>
__global__ __launch_bounds__(256) void k_gather8(const int* __restrict__ off,
                                                 const int* __restrict__ csr,
                                                 const float* __restrict__ dinv,
                                                 const unsigned short* __restrict__ hb,
                                                 const float* __restrict__ bias,
                                                 unsigned int* __restrict__ outp) {
    int idx = blockIdx.x * 256 + threadIdx.x;   // 8 lanes per node
    int n = idx >> 3;
    if (n >= NN) return;
    int c8 = idx & 7;                           // channels c8*8 .. c8*8+7
    const uint4* h4 = (const uint4*)hb;         // row stride = 8 uint4 (64 bf16)
    float dn = dinv[n];
    float acc[8];
    {
        uint4 v = h4[(size_t)n * 8 + c8];       // self term
        acc[0] = bf_lo(v.x); acc[1] = bf_hi(v.x);
        acc[2] = bf_lo(v.y); acc[3] = bf_hi(v.y);
        acc[4] = bf_lo(v.z); acc[5] = bf_hi(v.z);
        acc[6] = bf_lo(v.w); acc[7] = bf_hi(v.w);
    }
    int b = off[n], e = off[n + 1];
    int i = b;
    if (i < e) {
        int s = csr[i];
        for (++i; i < e; ++i) {
            int sn = csr[i];                    // prefetch next index
            uint4 v = h4[(size_t)s * 8 + c8];
            acc[0] += bf_lo(v.x); acc[1] += bf_hi(v.x);
            acc[2] += bf_lo(v.y); acc[3] += bf_hi(v.y);
            acc[4] += bf_lo(v.z); acc[5] += bf_hi(v.z);
            acc[6] += bf_lo(v.w); acc[7] += bf_hi(v.w);
            s = sn;
        }
        uint4 v = h4[(size_t)s * 8 + c8];
        acc[0] += bf_lo(v.x); acc[1] += bf_hi(v.x);
        acc[2] += bf_lo(v.y); acc[3] += bf_hi(v.y);
        acc[4] += bf_lo(v.z); acc[5] += bf_hi(v.z);
        acc[6] += bf_lo(v.w); acc[7] += bf_hi(v.w);
    }
    float o[8];
    if (RELU) {
        float4 b0 = ((const float4*)bias)[c8 * 2];
        float4 b1 = ((const float4*)bias)[c8 * 2 + 1];
        o[0] = dn * fmaxf(dn * acc[0] + b0.x, 0.f);
        o[1] = dn * fmaxf(dn * acc[1] + b0.y, 0.f);
        o[2] = dn * fmaxf(dn * acc[2] + b0.z, 0.f);
        o[3] = dn * fmaxf(dn * acc[3] + b0.w, 0.f);
        o[4] = dn * fmaxf(dn * acc[4] + b1.x, 0.f);
        o[5] = dn * fmaxf(dn * acc[5] + b1.y, 0.f);
        o[6] = dn * fmaxf(dn * acc[6] + b1.z, 0.f);
        o[7] = dn * fmaxf(dn * acc[7] + b1.w, 0.f);
    } else {
        #pragma unroll
        for (int j = 0; j < 8; ++j) o[j] = dn * acc[j];
    }
    uint4 p;
    p.x = (unsigned int)f2bf(o[0]) | ((unsigned int)f2bf(o[1]) << 16);
    p.y = (unsigned int)f2bf(o[2]) | ((unsigned int)f2bf(o[3]) << 16);
    p.z = (unsigned int)f2bf(o[4]) | ((unsigned int)f2bf(o[5]) << 16);
    p.w = (unsigned int)f2bf(o[6]) | ((unsigned int)f2bf(o[7]) << 16);
    ((uint4*)outp)[(size_t)n * 8 + c8] = p;
}

// ---------------- GEMM2: out1 = agg@W2+b2, out2 = agg@W3+b3 (agg in bf16) ----------------
__global__ __launch_bounds__(256) void k_gemm2(const unsigned short* __restrict__ aggb,
                                               const float* __restrict__ W2, const float* __restrict__ b2,
                                               const float* __restrict__ W3, const float* __restrict__ b3,
                                               float* __restrict__ out) {
    __shared__ float as_[64][72];     // +8 pad
    __shared__ float wc[64 * 64];
    __shared__ float bc[64];
    const int t = threadIdx.x;
    const int row0 = blockIdx.x * 64;
    const int nrows = min(64, NN - row0);

    #pragma unroll
    for (int i = 0; i < 16; ++i) {
        int f = t + i * 256;
        int k = f >> 6, c = f & 63;
        wc[f] = (c < 32) ? W2[k * 32 + c] : W3[k * 32 + (c - 32)];
    }
    if (t < 64) bc[t] = (t < 32) ? b2[t] : b3[t - 32];
    #pragma unroll
    for (int i = 0; i < 2; ++i) {
        int f = t + i * 256;           // 0..511
        int r = f >> 3, c8 = f & 7;
        uint4 v = make_uint4(0u, 0u, 0u, 0u);
        if (r < nrows) v = ((const uint4*)(aggb + (size_t)(row0 + r) * 64))[c8];
        float* dp = &as_[r][c8 * 8];
        dp[0] = bf_lo(v.x); dp[1] = bf_hi(v.x);
        dp[2] = bf_lo(v.y); dp[3] = bf_hi(v.y);
        dp[4] = bf_lo(v.z); dp[5] = bf_hi(v.z);
        dp[6] = bf_lo(v.w); dp[7] = bf_hi(v.w);
    }
    __syncthreads();

    const int tc = t & 15;
    const int tr = t >> 4;
    float acc[4][4];
    #pragma unroll
    for (int i = 0; i < 4; ++i)
        #pragma unroll
        for (int j = 0; j < 4; ++j) acc[i][j] = 0.f;

    #pragma unroll 4
    for (int k = 0; k < 64; ++k) {
        float4 wv = *(const float4*)&wc[k * 64 + tc * 4];
        #pragma unroll
        for (int i = 0; i < 4; ++i) {
            float xv = as_[tr * 4 + i][k];
            acc[i][0] += xv * wv.x; acc[i][1] += xv * wv.y;
            acc[i][2] += xv * wv.z; acc[i][3] += xv * wv.w;
        }
    }
    const int c0 = tc * 4;
    float4 bias = *(float4*)&bc[c0];
    #pragma unroll
    for (int i = 0; i < 4; ++i) {
        int r = tr * 4 + i;
        if (r < nrows) {
            float4 o = make_float4(acc[i][0] + bias.x, acc[i][1] + bias.y,
                                   acc[i][2] + bias.z, acc[i][3] + bias.w);
            size_t row = (size_t)(row0 + r);
            float* p = (tc < 8) ? (out + row * 32 + c0)
                                : (out + (size_t)NN * 32 + row * 32 + (c0 - 32));
            *(float4*)p = o;
        }
    }
}

extern "C" void kernel_launch(void* const* d_in, const int* in_sizes, int n_in,
                              void* d_out, int out_size, void* d_ws, size_t ws_size,
                              hipStream_t stream) {
    const float* x  = (const float*)d_in[0];
    const int* edges = (const int*)d_in[1];
    const float* W1 = (const float*)d_in[2];
    const float* b1 = (const float*)d_in[3];
    const float* W2 = (const float*)d_in[4];
    const float* b2 = (const float*)d_in[5];
    const float* W3 = (const float*)d_in[6];
    const float* b3 = (const float*)d_in[7];
    float* out = (float*)d_out;

    const int* srcs = edges;            // edges[0]
    const int* dsts = edges + NE;       // edges[1]

    // ws layout (4-byte words), total 8,201,184 words = 32.8 MB
    int*   csr_off = (int*)d_ws;                    // [NN+1]
    float* dinv    = (float*)((int*)d_ws + 100004); // [NN]
    int*   csr_src = (int*)d_ws + 200004;           // [NE]
    int*   bhist   = (int*)d_ws + 1800004;          // [NB]
    int*   boff    = (int*)d_ws + 1800396;          // [NB+1]
    int*   bcur    = (int*)d_ws + 1800788;          // [NB]
    // region A at 1801184 (16B aligned): pairs [NE uint] -> reused as t1b, then aggb
    unsigned int*   pairs = (unsigned int*)((int*)d_ws + 1801184);
    unsigned short* t1b   = (unsigned short*)pairs;  // [NN*64] bf16 (12.8 MB)
    unsigned short* aggb  = (unsigned short*)pairs;  // [NN*64] bf16 (t1b dead by then)
    // region B: h1b [NN*64] bf16
    unsigned short* h1b   = (unsigned short*)((int*)d_ws + 5001184);

    dim3 blk(256);
    const int gN8 = (NN * 8 + 255) / 256;   // 3125
    const int gT = (NN + 63) / 64;

    // CSR build: two-level counting sort (packed 4B pairs)
    hipMemsetAsync(bhist, 0, NB * sizeof(int), stream);
    k_hist<<<256, blk, 0, stream>>>(dsts, bhist);
    k_scanb<<<1, blk, 0, stream>>>(bhist, boff, bcur);
    k_bscatter<<<NCHUNK, dim3(512), 0, stream>>>(srcs, dsts, bcur, pairs);
    k_fine<<<NB, blk, 0, stream>>>(pairs, boff, csr_off, csr_src, dinv);

    // conv1: t1b = bf16(dinv*(x@W1)); h1b = bf16(dinv*relu(Agg(t1)+b1))
    k_gemm1<<<gT, blk, 0, stream>>>(x, W1, dinv, t1b);
    k_gather8<true><<<gN8, blk, 0, stream>>>(csr_off, csr_src, dinv, t1b, b1,
                                             (unsigned int*)h1b);
    // conv2/3 shared aggregation: aggb = bf16(Agg(h1)), then both GEMMs
    k_gather8<false><<<gN8, blk, 0, stream>>>(csr_off, csr_src, dinv, h1b, b1,
                                              (unsigned int*)aggb);
    k_gemm2<<<gT, blk, 0, stream>>>(aggb, W2, b2, W3, b3, out);
}

// Round 9
// 162.388 us; speedup vs baseline: 16.9740x; 1.1108x over previous
//
// GCNEncoder MI355X kernel — v6: MFMA bf16 GEMM1 (+W1 transpose prekernel);
// rebalanced 2-level sort + bf16 8-lane gather unchanged from v5.
#include <hip/hip_runtime.h>

#define NN 100000
#define NE 1600000
#define NB 391            // ceil(NN/256) buckets of 256 nodes (bucket = dst >> 8)
#define CHUNK 4096
#define NCHUNK 391        // ceil(NE/CHUNK)

typedef __attribute__((ext_vector_type(8))) short short8_t;
typedef __attribute__((ext_vector_type(4))) float float4_t;

// ---- bf16 helpers (RNE pack, bit-op unpack) ----
__device__ inline unsigned short f2bf(float f) {
    unsigned int u = __float_as_uint(f);
    unsigned int r = u + 0x7fffu + ((u >> 16) & 1u);
    return (unsigned short)(r >> 16);
}
__device__ inline float bf_lo(unsigned int u) { return __uint_as_float(u << 16); }
__device__ inline float bf_hi(unsigned int u) { return __uint_as_float(u & 0xffff0000u); }

// ---------------- Pass A: coarse histogram (LDS-privatized) ----------------
__global__ __launch_bounds__(256) void k_hist(const int* __restrict__ dst,
                                              int* __restrict__ bhist) {
    __shared__ int lh[NB];
    int t = threadIdx.x;
    for (int i = t; i < NB; i += 256) lh[i] = 0;
    __syncthreads();
    for (int e = blockIdx.x * 256 + t; e < NE; e += 256 * 256)
        atomicAdd(&lh[dst[e] >> 8], 1);
    __syncthreads();
    for (int i = t; i < NB; i += 256)
        if (lh[i]) atomicAdd(&bhist[i], lh[i]);
}

// ---------------- Pass B: scan buckets -> boff, bcursor ----------------
__global__ __launch_bounds__(256) void k_scanb(const int* __restrict__ bhist,
                                               int* __restrict__ boff,
                                               int* __restrict__ bcur) {
    __shared__ int sh[256];
    int t = threadIdx.x;
    int base = t * 2;
    int v0 = (base + 0 < NB) ? bhist[base + 0] : 0;
    int v1 = (base + 1 < NB) ? bhist[base + 1] : 0;
    int tsum = v0 + v1;
    sh[t] = tsum;
    __syncthreads();
    for (int d = 1; d < 256; d <<= 1) {
        int x = (t >= d) ? sh[t - d] : 0;
        __syncthreads();
        sh[t] += x;
        __syncthreads();
    }
    int excl = sh[t] - tsum;
    if (base + 0 < NB) { boff[base + 0] = excl;      bcur[base + 0] = excl; }
    if (base + 1 < NB) { boff[base + 1] = excl + v0; bcur[base + 1] = excl + v0; }
    if (t == 255) boff[NB] = sh[255];   // == NE
}

// ---------------- Pass C: chunked scatter into bucket regions (packed 4B) ----------------
// packed word = src (17 bits) | local_dst (8 bits) << 17
__global__ __launch_bounds__(512) void k_bscatter(const int* __restrict__ src,
                                                  const int* __restrict__ dst,
                                                  int* __restrict__ bcur,
                                                  unsigned int* __restrict__ pairs) {
    __shared__ int lh[NB];
    __shared__ int lbase[NB];
    int t = threadIdx.x;
    int e0 = blockIdx.x * CHUNK;
    int e1 = min(e0 + CHUNK, NE);
    for (int i = t; i < NB; i += 512) lh[i] = 0;
    __syncthreads();
    for (int e = e0 + t; e < e1; e += 512)
        atomicAdd(&lh[dst[e] >> 8], 1);
    __syncthreads();
    int rot = (int)((blockIdx.x * 97u) % NB);      // stagger global-atomic bursts
    for (int i = t; i < NB; i += 512) {
        int ii = i + rot; if (ii >= NB) ii -= NB;
        int h = lh[ii];
        lbase[ii] = h ? atomicAdd(&bcur[ii], h) : 0;
    }
    __syncthreads();
    for (int i = t; i < NB; i += 512) lh[i] = 0;   // reuse as cursor
    __syncthreads();
    for (int e = e0 + t; e < e1; e += 512) {
        int d = dst[e];
        int b = d >> 8;
        int r = atomicAdd(&lh[b], 1);
        pairs[lbase[b] + r] = (unsigned int)src[e] | ((unsigned int)(d & 255) << 17);
    }
}

// ---------------- Pass D: per-bucket fine sort + dinv + csr_off ----------------
__global__ __launch_bounds__(256) void k_fine(const unsigned int* __restrict__ pairs,
                                              const int* __restrict__ boff,
                                              int* __restrict__ csr_off,
                                              int* __restrict__ csr_src,
                                              float* __restrict__ dinv) {
    __shared__ int lcnt[256];
    __shared__ int sc[256];
    __shared__ int lofs[256];
    int t = threadIdx.x;
    int b = blockIdx.x;
    int n0 = b << 8;
    int nnode = min(256, NN - n0);
    int bO = boff[b], bE = boff[b + 1];

    lcnt[t] = 0;
    __syncthreads();
    for (int e = bO + t; e < bE; e += 256)
        atomicAdd(&lcnt[pairs[e] >> 17], 1);
    __syncthreads();
    sc[t] = lcnt[t];
    __syncthreads();
    for (int d = 1; d < 256; d <<= 1) {
        int x = (t >= d) ? sc[t - d] : 0;
        __syncthreads();
        sc[t] += x;
        __syncthreads();
    }
    {
        int excl = sc[t] - lcnt[t];
        lofs[t] = excl;
        if (t < nnode) {
            int n = n0 + t;
            csr_off[n] = bO + excl;
            dinv[n] = rsqrtf(1.0f + (float)lcnt[t]);
        }
        lcnt[t] = 0;   // reuse as cursor
    }
    if (b == NB - 1 && t == 0) csr_off[NN] = NE;
    __syncthreads();
    for (int e = bO + t; e < bE; e += 256) {
        unsigned int w = pairs[e];
        int li = (int)(w >> 17);
        int r = atomicAdd(&lcnt[li], 1);
        csr_src[bO + lofs[li] + r] = (int)(w & 0x1FFFFu);
    }
}

// ---------------- W1 transpose prekernel: wtb[c][k] = bf16(W1[k][c]) ----------------
__global__ __launch_bounds__(256) void k_w1t(const float* __restrict__ W1,
                                             unsigned short* __restrict__ wtb) {
    int f = blockIdx.x * 256 + threadIdx.x;      // 0..8191
    int c = f >> 7, k = f & 127;
    wtb[f] = f2bf(W1[k * 64 + c]);               // coalesced write, strided L2 read
}

// ---------------- GEMM1 (MFMA): t1b = bf16( dinv * (x @ W1) ) ----------------
// A = x tile [64 rows][128 k] bf16 in LDS (stride 136), B = wtb [64 col][128 k] bf16.
// Per block: 4 waves, wave w -> rows w*16..w*16+15, all 64 cols.
// mfma_f32_16x16x32_bf16: A row = l&15, k = (l>>4)*8+j; B col = l&15;
// C/D: col = l&15, row = (l>>4)*4 + reg  (verified layout, m89/m91).
__global__ __launch_bounds__(256) void k_gemm1(const float* __restrict__ x,
                                               const unsigned short* __restrict__ wtb,
                                               const float* __restrict__ dinv,
                                               unsigned short* __restrict__ t1b) {
    __shared__ __align__(16) unsigned short lx[64 * 136];
    __shared__ __align__(16) unsigned short lw[64 * 136];
    __shared__ float sdinv[64];
    const int t = threadIdx.x;
    const int row0 = blockIdx.x * 64;
    const int nrows = min(64, NN - row0);

    // stage x tile: 64 rows x 32 float4-chunks; convert to bf16
    #pragma unroll
    for (int i = 0; i < 8; ++i) {
        int f = t + i * 256;            // 0..2047
        int r = f >> 5, c4 = f & 31;
        float4 v = make_float4(0.f, 0.f, 0.f, 0.f);
        if (r < nrows) v = ((const float4*)(x + (size_t)(row0 + r) * 128))[c4];
        ushort4 o;
        o.x = f2bf(v.x); o.y = f2bf(v.y); o.z = f2bf(v.z); o.w = f2bf(v.w);
        *(ushort4*)&lx[r * 136 + c4 * 4] = o;
    }
    // stage wtb: 64 cols x 16 uint4-chunks (already bf16)
    #pragma unroll
    for (int i = 0; i < 4; ++i) {
        int f = t + i * 256;            // 0..1023 ; f = c*16 + c8
        int c = f >> 4, c8 = f & 15;
        uint4 v = ((const uint4*)wtb)[f];
        *(uint4*)&lw[c * 136 + c8 * 8] = v;
    }
    if (t < 64) sdinv[t] = (row0 + t < NN) ? dinv[row0 + t] : 0.f;
    __syncthreads();

    const int w = t >> 6, l = t & 63;
    const int m15 = l & 15, kg = l >> 4;
    const unsigned short* pa = &lx[(w * 16 + m15) * 136 + kg * 8];
    const unsigned short* pb = &lw[m15 * 136 + kg * 8];

    float4_t acc[4];
    #pragma unroll
    for (int cb = 0; cb < 4; ++cb) acc[cb] = (float4_t){0.f, 0.f, 0.f, 0.f};

    #pragma unroll
    for (int ks = 0; ks < 4; ++ks) {
        short8_t a = *(const short8_t*)(pa + ks * 32);
        #pragma unroll
        for (int cb = 0; cb < 4; ++cb) {
            short8_t b = *(const short8_t*)(pb + cb * (16 * 136) + ks * 32);
            acc[cb] = __builtin_amdgcn_mfma_f32_16x16x32_bf16(a, b, acc[cb], 0, 0, 0);
        }
    }

    #pragma unroll
    for (int r = 0; r < 4; ++r) {
        int lrow = w * 16 + kg * 4 + r;
        if (lrow < nrows) {
            float dn = sdinv[lrow];
            size_t grow = (size_t)(row0 + lrow);
            #pragma unroll
            for (int cb = 0; cb < 4; ++cb)
                t1b[grow * 64 + cb * 16 + m15] = f2bf(acc[cb][r] * dn);
        }
    }
}

// ---------------- bf16 gather aggregation (8 lanes/node, 8 ch/lane) ----------------
template <bool RELU>
__global__ __launch_bounds__(256) void k_gather8(const int* __restrict__ off,
                                                 const int* __restrict__ csr,
                                                 const float* __restrict__ dinv,
                                                 const unsigned short* __restrict__ hb,
                                                 const float* __restrict__ bias,
                                                 unsigned int* __restrict__ outp) {
    int idx = blockIdx.x * 256 + threadIdx.x;   // 8 lanes per node
    int n = idx >> 3;
    if (n >= NN) return;
    int c8 = idx & 7;                           // channels c8*8 .. c8*8+7
    const uint4* h4 = (const uint4*)hb;         // row stride = 8 uint4 (64 bf16)
    float dn = dinv[n];
    float acc[8];
    {
        uint4 v = h4[(size_t)n * 8 + c8];       // self term
        acc[0] = bf_lo(v.x); acc[1] = bf_hi(v.x);
        acc[2] = bf_lo(v.y); acc[3] = bf_hi(v.y);
        acc[4] = bf_lo(v.z); acc[5] = bf_hi(v.z);
        acc[6] = bf_lo(v.w); acc[7] = bf_hi(v.w);
    }
    int b = off[n], e = off[n + 1];
    int i = b;
    if (i < e) {
        int s = csr[i];
        for (++i; i < e; ++i) {
            int sn = csr[i];                    // prefetch next index
            uint4 v = h4[(size_t)s * 8 + c8];
            acc[0] += bf_lo(v.x); acc[1] += bf_hi(v.x);
            acc[2] += bf_lo(v.y); acc[3] += bf_hi(v.y);
            acc[4] += bf_lo(v.z); acc[5] += bf_hi(v.z);
            acc[6] += bf_lo(v.w); acc[7] += bf_hi(v.w);
            s = sn;
        }
        uint4 v = h4[(size_t)s * 8 + c8];
        acc[0] += bf_lo(v.x); acc[1] += bf_hi(v.x);
        acc[2] += bf_lo(v.y); acc[3] += bf_hi(v.y);
        acc[4] += bf_lo(v.z); acc[5] += bf_hi(v.z);
        acc[6] += bf_lo(v.w); acc[7] += bf_hi(v.w);
    }
    float o[8];
    if (RELU) {
        float4 b0 = ((const float4*)bias)[c8 * 2];
        float4 b1 = ((const float4*)bias)[c8 * 2 + 1];
        o[0] = dn * fmaxf(dn * acc[0] + b0.x, 0.f);
        o[1] = dn * fmaxf(dn * acc[1] + b0.y, 0.f);
        o[2] = dn * fmaxf(dn * acc[2] + b0.z, 0.f);
        o[3] = dn * fmaxf(dn * acc[3] + b0.w, 0.f);
        o[4] = dn * fmaxf(dn * acc[4] + b1.x, 0.f);
        o[5] = dn * fmaxf(dn * acc[5] + b1.y, 0.f);
        o[6] = dn * fmaxf(dn * acc[6] + b1.z, 0.f);
        o[7] = dn * fmaxf(dn * acc[7] + b1.w, 0.f);
    } else {
        #pragma unroll
        for (int j = 0; j < 8; ++j) o[j] = dn * acc[j];
    }
    uint4 p;
    p.x = (unsigned int)f2bf(o[0]) | ((unsigned int)f2bf(o[1]) << 16);
    p.y = (unsigned int)f2bf(o[2]) | ((unsigned int)f2bf(o[3]) << 16);
    p.z = (unsigned int)f2bf(o[4]) | ((unsigned int)f2bf(o[5]) << 16);
    p.w = (unsigned int)f2bf(o[6]) | ((unsigned int)f2bf(o[7]) << 16);
    ((uint4*)outp)[(size_t)n * 8 + c8] = p;
}

// ---------------- GEMM2: out1 = agg@W2+b2, out2 = agg@W3+b3 (agg in bf16) ----------------
__global__ __launch_bounds__(256) void k_gemm2(const unsigned short* __restrict__ aggb,
                                               const float* __restrict__ W2, const float* __restrict__ b2,
                                               const float* __restrict__ W3, const float* __restrict__ b3,
                                               float* __restrict__ out) {
    __shared__ float as_[64][72];     // +8 pad
    __shared__ float wc[64 * 64];
    __shared__ float bc[64];
    const int t = threadIdx.x;
    const int row0 = blockIdx.x * 64;
    const int nrows = min(64, NN - row0);

    #pragma unroll
    for (int i = 0; i < 16; ++i) {
        int f = t + i * 256;
        int k = f >> 6, c = f & 63;
        wc[f] = (c < 32) ? W2[k * 32 + c] : W3[k * 32 + (c - 32)];
    }
    if (t < 64) bc[t] = (t < 32) ? b2[t] : b3[t - 32];
    #pragma unroll
    for (int i = 0; i < 2; ++i) {
        int f = t + i * 256;           // 0..511
        int r = f >> 3, c8 = f & 7;
        uint4 v = make_uint4(0u, 0u, 0u, 0u);
        if (r < nrows) v = ((const uint4*)(aggb + (size_t)(row0 + r) * 64))[c8];
        float* dp = &as_[r][c8 * 8];
        dp[0] = bf_lo(v.x); dp[1] = bf_hi(v.x);
        dp[2] = bf_lo(v.y); dp[3] = bf_hi(v.y);
        dp[4] = bf_lo(v.z); dp[5] = bf_hi(v.z);
        dp[6] = bf_lo(v.w); dp[7] = bf_hi(v.w);
    }
    __syncthreads();

    const int tc = t & 15;
    const int tr = t >> 4;
    float acc[4][4];
    #pragma unroll
    for (int i = 0; i < 4; ++i)
        #pragma unroll
        for (int j = 0; j < 4; ++j) acc[i][j] = 0.f;

    #pragma unroll 4
    for (int k = 0; k < 64; ++k) {
        float4 wv = *(const float4*)&wc[k * 64 + tc * 4];
        #pragma unroll
        for (int i = 0; i < 4; ++i) {
            float xv = as_[tr * 4 + i][k];
            acc[i][0] += xv * wv.x; acc[i][1] += xv * wv.y;
            acc[i][2] += xv * wv.z; acc[i][3] += xv * wv.w;
        }
    }
    const int c0 = tc * 4;
    float4 bias = *(float4*)&bc[c0];
    #pragma unroll
    for (int i = 0; i < 4; ++i) {
        int r = tr * 4 + i;
        if (r < nrows) {
            float4 o = make_float4(acc[i][0] + bias.x, acc[i][1] + bias.y,
                                   acc[i][2] + bias.z, acc[i][3] + bias.w);
            size_t row = (size_t)(row0 + r);
            float* p = (tc < 8) ? (out + row * 32 + c0)
                                : (out + (size_t)NN * 32 + row * 32 + (c0 - 32));
            *(float4*)p = o;
        }
    }
}

extern "C" void kernel_launch(void* const* d_in, const int* in_sizes, int n_in,
                              void* d_out, int out_size, void* d_ws, size_t ws_size,
                              hipStream_t stream) {
    const float* x  = (const float*)d_in[0];
    const int* edges = (const int*)d_in[1];
    const float* W1 = (const float*)d_in[2];
    const float* b1 = (const float*)d_in[3];
    const float* W2 = (const float*)d_in[4];
    const float* b2 = (const float*)d_in[5];
    const float* W3 = (const float*)d_in[6];
    const float* b3 = (const float*)d_in[7];
    float* out = (float*)d_out;

    const int* srcs = edges;            // edges[0]
    const int* dsts = edges + NE;       // edges[1]

    // ws layout (4-byte words), total 8,205,280 words = 32.8 MB
    int*   csr_off = (int*)d_ws;                    // [NN+1]
    float* dinv    = (float*)((int*)d_ws + 100004); // [NN]
    int*   csr_src = (int*)d_ws + 200004;           // [NE]
    int*   bhist   = (int*)d_ws + 1800004;          // [NB]
    int*   boff    = (int*)d_ws + 1800396;          // [NB+1]
    int*   bcur    = (int*)d_ws + 1800788;          // [NB]
    unsigned short* wtb = (unsigned short*)((int*)d_ws + 1801184); // [64*128] bf16 (16KB)
    // region A at 1805280 (16B aligned): pairs [NE uint] -> reused as t1b, then aggb
    unsigned int*   pairs = (unsigned int*)((int*)d_ws + 1805280);
    unsigned short* t1b   = (unsigned short*)pairs;  // [NN*64] bf16 (12.8 MB)
    unsigned short* aggb  = (unsigned short*)pairs;  // [NN*64] bf16 (t1b dead by then)
    // region B: h1b [NN*64] bf16
    unsigned short* h1b   = (unsigned short*)((int*)d_ws + 5005280);

    dim3 blk(256);
    const int gN8 = (NN * 8 + 255) / 256;   // 3125
    const int gT = (NN + 63) / 64;

    // CSR build: two-level counting sort (packed 4B pairs) + W1 transpose
    hipMemsetAsync(bhist, 0, NB * sizeof(int), stream);
    k_hist<<<256, blk, 0, stream>>>(dsts, bhist);
    k_w1t<<<32, blk, 0, stream>>>(W1, wtb);
    k_scanb<<<1, blk, 0, stream>>>(bhist, boff, bcur);
    k_bscatter<<<NCHUNK, dim3(512), 0, stream>>>(srcs, dsts, bcur, pairs);
    k_fine<<<NB, blk, 0, stream>>>(pairs, boff, csr_off, csr_src, dinv);

    // conv1: t1b = bf16(dinv*(x@W1)) via MFMA; h1b = bf16(dinv*relu(Agg(t1)+b1))
    k_gemm1<<<gT, blk, 0, stream>>>(x, wtb, dinv, t1b);
    k_gather8<true><<<gN8, blk, 0, stream>>>(csr_off, csr_src, dinv, t1b, b1,
                                             (unsigned int*)h1b);
    // conv2/3 shared aggregation: aggb = bf16(Agg(h1)), then both GEMMs
    k_gather8<false><<<gN8, blk, 0, stream>>>(csr_off, csr_src, dinv, h1b, b1,
                                              (unsigned int*)aggb);
    k_gemm2<<<gT, blk, 0, stream>>>(aggb, W2, b2, W3, b3, out);
}

// Round 10
// 158.361 us; speedup vs baseline: 17.4057x; 1.0254x over previous
//
// GCNEncoder MI355X kernel — v7: fused gather2+GEMM2 (k_gg2); gemm1 128-row/512-thr;
// sort + gather1 unchanged from v6.
#include <hip/hip_runtime.h>

#define NN 100000
#define NE 1600000
#define NB 391            // ceil(NN/256) buckets of 256 nodes (bucket = dst >> 8)
#define CHUNK 4096
#define NCHUNK 391        // ceil(NE/CHUNK)

typedef __attribute__((ext_vector_type(8))) short short8_t;
typedef __attribute__((ext_vector_type(4))) float float4_t;

// ---- bf16 helpers (RNE pack, bit-op unpack) ----
__device__ inline unsigned short f2bf(float f) {
    unsigned int u = __float_as_uint(f);
    unsigned int r = u + 0x7fffu + ((u >> 16) & 1u);
    return (unsigned short)(r >> 16);
}
__device__ inline float bf_lo(unsigned int u) { return __uint_as_float(u << 16); }
__device__ inline float bf_hi(unsigned int u) { return __uint_as_float(u & 0xffff0000u); }

// ---------------- Pass A: coarse histogram (LDS-privatized) ----------------
__global__ __launch_bounds__(256) void k_hist(const int* __restrict__ dst,
                                              int* __restrict__ bhist) {
    __shared__ int lh[NB];
    int t = threadIdx.x;
    for (int i = t; i < NB; i += 256) lh[i] = 0;
    __syncthreads();
    for (int e = blockIdx.x * 256 + t; e < NE; e += 256 * 256)
        atomicAdd(&lh[dst[e] >> 8], 1);
    __syncthreads();
    for (int i = t; i < NB; i += 256)
        if (lh[i]) atomicAdd(&bhist[i], lh[i]);
}

// ---------------- Pass B: scan buckets -> boff, bcursor ----------------
__global__ __launch_bounds__(256) void k_scanb(const int* __restrict__ bhist,
                                               int* __restrict__ boff,
                                               int* __restrict__ bcur) {
    __shared__ int sh[256];
    int t = threadIdx.x;
    int base = t * 2;
    int v0 = (base + 0 < NB) ? bhist[base + 0] : 0;
    int v1 = (base + 1 < NB) ? bhist[base + 1] : 0;
    int tsum = v0 + v1;
    sh[t] = tsum;
    __syncthreads();
    for (int d = 1; d < 256; d <<= 1) {
        int x = (t >= d) ? sh[t - d] : 0;
        __syncthreads();
        sh[t] += x;
        __syncthreads();
    }
    int excl = sh[t] - tsum;
    if (base + 0 < NB) { boff[base + 0] = excl;      bcur[base + 0] = excl; }
    if (base + 1 < NB) { boff[base + 1] = excl + v0; bcur[base + 1] = excl + v0; }
    if (t == 255) boff[NB] = sh[255];   // == NE
}

// ---------------- Pass C: chunked scatter into bucket regions (packed 4B) ----------------
// packed word = src (17 bits) | local_dst (8 bits) << 17
__global__ __launch_bounds__(512) void k_bscatter(const int* __restrict__ src,
                                                  const int* __restrict__ dst,
                                                  int* __restrict__ bcur,
                                                  unsigned int* __restrict__ pairs) {
    __shared__ int lh[NB];
    __shared__ int lbase[NB];
    int t = threadIdx.x;
    int e0 = blockIdx.x * CHUNK;
    int e1 = min(e0 + CHUNK, NE);
    for (int i = t; i < NB; i += 512) lh[i] = 0;
    __syncthreads();
    for (int e = e0 + t; e < e1; e += 512)
        atomicAdd(&lh[dst[e] >> 8], 1);
    __syncthreads();
    int rot = (int)((blockIdx.x * 97u) % NB);      // stagger global-atomic bursts
    for (int i = t; i < NB; i += 512) {
        int ii = i + rot; if (ii >= NB) ii -= NB;
        int h = lh[ii];
        lbase[ii] = h ? atomicAdd(&bcur[ii], h) : 0;
    }
    __syncthreads();
    for (int i = t; i < NB; i += 512) lh[i] = 0;   // reuse as cursor
    __syncthreads();
    for (int e = e0 + t; e < e1; e += 512) {
        int d = dst[e];
        int b = d >> 8;
        int r = atomicAdd(&lh[b], 1);
        pairs[lbase[b] + r] = (unsigned int)src[e] | ((unsigned int)(d & 255) << 17);
    }
}

// ---------------- Pass D: per-bucket fine sort + dinv + csr_off ----------------
__global__ __launch_bounds__(256) void k_fine(const unsigned int* __restrict__ pairs,
                                              const int* __restrict__ boff,
                                              int* __restrict__ csr_off,
                                              int* __restrict__ csr_src,
                                              float* __restrict__ dinv) {
    __shared__ int lcnt[256];
    __shared__ int sc[256];
    __shared__ int lofs[256];
    int t = threadIdx.x;
    int b = blockIdx.x;
    int n0 = b << 8;
    int nnode = min(256, NN - n0);
    int bO = boff[b], bE = boff[b + 1];

    lcnt[t] = 0;
    __syncthreads();
    for (int e = bO + t; e < bE; e += 256)
        atomicAdd(&lcnt[pairs[e] >> 17], 1);
    __syncthreads();
    sc[t] = lcnt[t];
    __syncthreads();
    for (int d = 1; d < 256; d <<= 1) {
        int x = (t >= d) ? sc[t - d] : 0;
        __syncthreads();
        sc[t] += x;
        __syncthreads();
    }
    {
        int excl = sc[t] - lcnt[t];
        lofs[t] = excl;
        if (t < nnode) {
            int n = n0 + t;
            csr_off[n] = bO + excl;
            dinv[n] = rsqrtf(1.0f + (float)lcnt[t]);
        }
        lcnt[t] = 0;   // reuse as cursor
    }
    if (b == NB - 1 && t == 0) csr_off[NN] = NE;
    __syncthreads();
    for (int e = bO + t; e < bE; e += 256) {
        unsigned int w = pairs[e];
        int li = (int)(w >> 17);
        int r = atomicAdd(&lcnt[li], 1);
        csr_src[bO + lofs[li] + r] = (int)(w & 0x1FFFFu);
    }
}

// ---------------- W1 transpose prekernel: wtb[c][k] = bf16(W1[k][c]) ----------------
__global__ __launch_bounds__(256) void k_w1t(const float* __restrict__ W1,
                                             unsigned short* __restrict__ wtb) {
    int f = blockIdx.x * 256 + threadIdx.x;      // 0..8191
    int c = f >> 7, k = f & 127;
    wtb[f] = f2bf(W1[k * 64 + c]);               // coalesced write, strided L2 read
}

// ---------------- GEMM1 (MFMA): t1b = bf16( dinv * (x @ W1) ) ----------------
// 128-row tile, 512 threads (8 waves); wave w -> rows w*16..w*16+15, all 64 cols.
// mfma_f32_16x16x32_bf16: A row = l&15, k = (l>>4)*8+j; B col = l&15;
// C/D: col = l&15, row = (l>>4)*4 + reg  (verified layout, m89/m91).
__global__ __launch_bounds__(512) void k_gemm1(const float* __restrict__ x,
                                               const unsigned short* __restrict__ wtb,
                                               const float* __restrict__ dinv,
                                               unsigned short* __restrict__ t1b) {
    __shared__ __align__(16) unsigned short lx[128 * 136];
    __shared__ __align__(16) unsigned short lw[64 * 136];
    __shared__ float sdinv[128];
    const int t = threadIdx.x;
    const int row0 = blockIdx.x * 128;
    const int nrows = min(128, NN - row0);

    // stage x tile: 128 rows x 32 float4-chunks; convert to bf16
    #pragma unroll
    for (int i = 0; i < 8; ++i) {
        int f = t + i * 512;            // 0..4095
        int r = f >> 5, c4 = f & 31;
        float4 v = make_float4(0.f, 0.f, 0.f, 0.f);
        if (r < nrows) v = ((const float4*)(x + (size_t)(row0 + r) * 128))[c4];
        ushort4 o;
        o.x = f2bf(v.x); o.y = f2bf(v.y); o.z = f2bf(v.z); o.w = f2bf(v.w);
        *(ushort4*)&lx[r * 136 + c4 * 4] = o;
    }
    // stage wtb: 64 cols x 16 uint4-chunks (already bf16)
    #pragma unroll
    for (int i = 0; i < 2; ++i) {
        int f = t + i * 512;            // 0..1023 ; f = c*16 + c8
        int c = f >> 4, c8 = f & 15;
        uint4 v = ((const uint4*)wtb)[f];
        *(uint4*)&lw[c * 136 + c8 * 8] = v;
    }
    if (t < 128) sdinv[t] = (row0 + t < NN) ? dinv[row0 + t] : 0.f;
    __syncthreads();

    const int w = t >> 6, l = t & 63;
    const int m15 = l & 15, kg = l >> 4;
    const unsigned short* pa = &lx[(w * 16 + m15) * 136 + kg * 8];
    const unsigned short* pb = &lw[m15 * 136 + kg * 8];

    float4_t acc[4];
    #pragma unroll
    for (int cb = 0; cb < 4; ++cb) acc[cb] = (float4_t){0.f, 0.f, 0.f, 0.f};

    #pragma unroll
    for (int ks = 0; ks < 4; ++ks) {
        short8_t a = *(const short8_t*)(pa + ks * 32);
        #pragma unroll
        for (int cb = 0; cb < 4; ++cb) {
            short8_t b = *(const short8_t*)(pb + cb * (16 * 136) + ks * 32);
            acc[cb] = __builtin_amdgcn_mfma_f32_16x16x32_bf16(a, b, acc[cb], 0, 0, 0);
        }
    }

    #pragma unroll
    for (int r = 0; r < 4; ++r) {
        int lrow = w * 16 + kg * 4 + r;
        if (lrow < nrows) {
            float dn = sdinv[lrow];
            size_t grow = (size_t)(row0 + lrow);
            #pragma unroll
            for (int cb = 0; cb < 4; ++cb)
                t1b[grow * 64 + cb * 16 + m15] = f2bf(acc[cb][r] * dn);
        }
    }
}

// ---------------- bf16 gather aggregation (8 lanes/node, 8 ch/lane) ----------------
template <bool RELU>
__global__ __launch_bounds__(256) void k_gather8(const int* __restrict__ off,
                                                 const int* __restrict__ csr,
                                                 const float* __restrict__ dinv,
                                                 const unsigned short* __restrict__ hb,
                                                 const float* __restrict__ bias,
                                                 unsigned int* __restrict__ outp) {
    int idx = blockIdx.x * 256 + threadIdx.x;   // 8 lanes per node
    int n = idx >> 3;
    if (n >= NN) return;
    int c8 = idx & 7;                           // channels c8*8 .. c8*8+7
    const uint4* h4 = (const uint4*)hb;         // row stride = 8 uint4 (64 bf16)
    float dn = dinv[n];
    float acc[8];
    {
        uint4 v = h4[(size_t)n * 8 + c8];       // self term
        acc[0] = bf_lo(v.x); acc[1] = bf_hi(v.x);
        acc[2] = bf_lo(v.y); acc[3] = bf_hi(v.y);
        acc[4] = bf_lo(v.z); acc[5] = bf_hi(v.z);
        acc[6] = bf_lo(v.w); acc[7] = bf_hi(v.w);
    }
    int b = off[n], e = off[n + 1];
    int i = b;
    if (i < e) {
        int s = csr[i];
        for (++i; i < e; ++i) {
            int sn = csr[i];                    // prefetch next index
            uint4 v = h4[(size_t)s * 8 + c8];
            acc[0] += bf_lo(v.x); acc[1] += bf_hi(v.x);
            acc[2] += bf_lo(v.y); acc[3] += bf_hi(v.y);
            acc[4] += bf_lo(v.z); acc[5] += bf_hi(v.z);
            acc[6] += bf_lo(v.w); acc[7] += bf_hi(v.w);
            s = sn;
        }
        uint4 v = h4[(size_t)s * 8 + c8];
        acc[0] += bf_lo(v.x); acc[1] += bf_hi(v.x);
        acc[2] += bf_lo(v.y); acc[3] += bf_hi(v.y);
        acc[4] += bf_lo(v.z); acc[5] += bf_hi(v.z);
        acc[6] += bf_lo(v.w); acc[7] += bf_hi(v.w);
    }
    float o[8];
    if (RELU) {
        float4 b0 = ((const float4*)bias)[c8 * 2];
        float4 b1 = ((const float4*)bias)[c8 * 2 + 1];
        o[0] = dn * fmaxf(dn * acc[0] + b0.x, 0.f);
        o[1] = dn * fmaxf(dn * acc[1] + b0.y, 0.f);
        o[2] = dn * fmaxf(dn * acc[2] + b0.z, 0.f);
        o[3] = dn * fmaxf(dn * acc[3] + b0.w, 0.f);
        o[4] = dn * fmaxf(dn * acc[4] + b1.x, 0.f);
        o[5] = dn * fmaxf(dn * acc[5] + b1.y, 0.f);
        o[6] = dn * fmaxf(dn * acc[6] + b1.z, 0.f);
        o[7] = dn * fmaxf(dn * acc[7] + b1.w, 0.f);
    } else {
        #pragma unroll
        for (int j = 0; j < 8; ++j) o[j] = dn * acc[j];
    }
    uint4 p;
    p.x = (unsigned int)f2bf(o[0]) | ((unsigned int)f2bf(o[1]) << 16);
    p.y = (unsigned int)f2bf(o[2]) | ((unsigned int)f2bf(o[3]) << 16);
    p.z = (unsigned int)f2bf(o[4]) | ((unsigned int)f2bf(o[5]) << 16);
    p.w = (unsigned int)f2bf(o[6]) | ((unsigned int)f2bf(o[7]) << 16);
    ((uint4*)outp)[(size_t)n * 8 + c8] = p;
}

// ---------------- Fused gather2 + GEMM2: out = [Agg(h1)@W2+b2 | Agg(h1)@W3+b3] ----------------
// Phase A: 4 lanes/node x 16 ch gather h1' (bf16) -> fp32 LDS tile (64 rows).
// Phase B: 4x4-microtile VALU GEMM vs combined [64][64] weights.
__global__ __launch_bounds__(256) void k_gg2(const int* __restrict__ off,
                                             const int* __restrict__ csr,
                                             const float* __restrict__ dinv,
                                             const unsigned short* __restrict__ hb,
                                             const float* __restrict__ W2, const float* __restrict__ b2,
                                             const float* __restrict__ W3, const float* __restrict__ b3,
                                             float* __restrict__ out) {
    __shared__ float as_[64][72];     // +8 pad
    __shared__ float wc[64 * 64];
    __shared__ float bc[64];
    const int t = threadIdx.x;
    const int row0 = blockIdx.x * 64;
    const int nrows = min(64, NN - row0);

    // stage combined weights
    #pragma unroll
    for (int i = 0; i < 16; ++i) {
        int f = t + i * 256;
        int k = f >> 6, c = f & 63;
        wc[f] = (c < 32) ? W2[k * 32 + c] : W3[k * 32 + (c - 32)];
    }
    if (t < 64) bc[t] = (t < 32) ? b2[t] : b3[t - 32];

    // phase A: gather agg2 rows straight into LDS (fp32)
    {
        const int nl = t >> 2;              // 0..63
        const int n = row0 + nl;
        const int c16 = t & 3;              // channels c16*16 .. +15
        float acc[16];
        if (n < NN) {
            const uint4* h4 = (const uint4*)hb;
            float dn = dinv[n];
            size_t base = (size_t)n * 8 + c16 * 2;
            uint4 v0 = h4[base], v1 = h4[base + 1];
            acc[0]  = bf_lo(v0.x); acc[1]  = bf_hi(v0.x);
            acc[2]  = bf_lo(v0.y); acc[3]  = bf_hi(v0.y);
            acc[4]  = bf_lo(v0.z); acc[5]  = bf_hi(v0.z);
            acc[6]  = bf_lo(v0.w); acc[7]  = bf_hi(v0.w);
            acc[8]  = bf_lo(v1.x); acc[9]  = bf_hi(v1.x);
            acc[10] = bf_lo(v1.y); acc[11] = bf_hi(v1.y);
            acc[12] = bf_lo(v1.z); acc[13] = bf_hi(v1.z);
            acc[14] = bf_lo(v1.w); acc[15] = bf_hi(v1.w);
            int b = off[n], e = off[n + 1];
            int i = b;
            if (i < e) {
                int s = csr[i];
                for (++i; i < e; ++i) {
                    int sn = csr[i];            // prefetch next index
                    size_t sb = (size_t)s * 8 + c16 * 2;
                    uint4 w0 = h4[sb], w1 = h4[sb + 1];
                    acc[0]  += bf_lo(w0.x); acc[1]  += bf_hi(w0.x);
                    acc[2]  += bf_lo(w0.y); acc[3]  += bf_hi(w0.y);
                    acc[4]  += bf_lo(w0.z); acc[5]  += bf_hi(w0.z);
                    acc[6]  += bf_lo(w0.w); acc[7]  += bf_hi(w0.w);
                    acc[8]  += bf_lo(w1.x); acc[9]  += bf_hi(w1.x);
                    acc[10] += bf_lo(w1.y); acc[11] += bf_hi(w1.y);
                    acc[12] += bf_lo(w1.z); acc[13] += bf_hi(w1.z);
                    acc[14] += bf_lo(w1.w); acc[15] += bf_hi(w1.w);
                    s = sn;
                }
                size_t sb = (size_t)s * 8 + c16 * 2;
                uint4 w0 = h4[sb], w1 = h4[sb + 1];
                acc[0]  += bf_lo(w0.x); acc[1]  += bf_hi(w0.x);
                acc[2]  += bf_lo(w0.y); acc[3]  += bf_hi(w0.y);
                acc[4]  += bf_lo(w0.z); acc[5]  += bf_hi(w0.z);
                acc[6]  += bf_lo(w0.w); acc[7]  += bf_hi(w0.w);
                acc[8]  += bf_lo(w1.x); acc[9]  += bf_hi(w1.x);
                acc[10] += bf_lo(w1.y); acc[11] += bf_hi(w1.y);
                acc[12] += bf_lo(w1.z); acc[13] += bf_hi(w1.z);
                acc[14] += bf_lo(w1.w); acc[15] += bf_hi(w1.w);
            }
            #pragma unroll
            for (int j = 0; j < 16; ++j) acc[j] *= dn;
        } else {
            #pragma unroll
            for (int j = 0; j < 16; ++j) acc[j] = 0.f;
        }
        float* dp = &as_[nl][c16 * 16];
        #pragma unroll
        for (int j = 0; j < 16; ++j) dp[j] = acc[j];
    }
    __syncthreads();

    // phase B: GEMM
    const int tc = t & 15;
    const int tr = t >> 4;
    float acc[4][4];
    #pragma unroll
    for (int i = 0; i < 4; ++i)
        #pragma unroll
        for (int j = 0; j < 4; ++j) acc[i][j] = 0.f;

    #pragma unroll 4
    for (int k = 0; k < 64; ++k) {
        float4 wv = *(const float4*)&wc[k * 64 + tc * 4];
        #pragma unroll
        for (int i = 0; i < 4; ++i) {
            float xv = as_[tr * 4 + i][k];
            acc[i][0] += xv * wv.x; acc[i][1] += xv * wv.y;
            acc[i][2] += xv * wv.z; acc[i][3] += xv * wv.w;
        }
    }
    const int c0 = tc * 4;
    float4 bias = *(float4*)&bc[c0];
    #pragma unroll
    for (int i = 0; i < 4; ++i) {
        int r = tr * 4 + i;
        if (r < nrows) {
            float4 o = make_float4(acc[i][0] + bias.x, acc[i][1] + bias.y,
                                   acc[i][2] + bias.z, acc[i][3] + bias.w);
            size_t row = (size_t)(row0 + r);
            float* p = (tc < 8) ? (out + row * 32 + c0)
                                : (out + (size_t)NN * 32 + row * 32 + (c0 - 32));
            *(float4*)p = o;
        }
    }
}

extern "C" void kernel_launch(void* const* d_in, const int* in_sizes, int n_in,
                              void* d_out, int out_size, void* d_ws, size_t ws_size,
                              hipStream_t stream) {
    const float* x  = (const float*)d_in[0];
    const int* edges = (const int*)d_in[1];
    const float* W1 = (const float*)d_in[2];
    const float* b1 = (const float*)d_in[3];
    const float* W2 = (const float*)d_in[4];
    const float* b2 = (const float*)d_in[5];
    const float* W3 = (const float*)d_in[6];
    const float* b3 = (const float*)d_in[7];
    float* out = (float*)d_out;

    const int* srcs = edges;            // edges[0]
    const int* dsts = edges + NE;       // edges[1]

    // ws layout (4-byte words)
    int*   csr_off = (int*)d_ws;                    // [NN+1]
    float* dinv    = (float*)((int*)d_ws + 100004); // [NN]
    int*   csr_src = (int*)d_ws + 200004;           // [NE]
    int*   bhist   = (int*)d_ws + 1800004;          // [NB]
    int*   boff    = (int*)d_ws + 1800396;          // [NB+1]
    int*   bcur    = (int*)d_ws + 1800788;          // [NB]
    unsigned short* wtb = (unsigned short*)((int*)d_ws + 1801184); // [64*128] bf16 (16KB)
    // region A at 1805280 (16B aligned): pairs [NE uint] -> reused as t1b
    unsigned int*   pairs = (unsigned int*)((int*)d_ws + 1805280);
    unsigned short* t1b   = (unsigned short*)pairs;  // [NN*64] bf16 (12.8 MB)
    // region B: h1b [NN*64] bf16
    unsigned short* h1b   = (unsigned short*)((int*)d_ws + 5005280);

    dim3 blk(256);
    const int gN8 = (NN * 8 + 255) / 256;   // 3125
    const int gT  = (NN + 63) / 64;         // 1563
    const int gT1 = (NN + 127) / 128;       // 782

    // CSR build: two-level counting sort (packed 4B pairs) + W1 transpose
    hipMemsetAsync(bhist, 0, NB * sizeof(int), stream);
    k_hist<<<256, blk, 0, stream>>>(dsts, bhist);
    k_w1t<<<32, blk, 0, stream>>>(W1, wtb);
    k_scanb<<<1, blk, 0, stream>>>(bhist, boff, bcur);
    k_bscatter<<<NCHUNK, dim3(512), 0, stream>>>(srcs, dsts, bcur, pairs);
    k_fine<<<NB, blk, 0, stream>>>(pairs, boff, csr_off, csr_src, dinv);

    // conv1: t1b = bf16(dinv*(x@W1)) via MFMA; h1b = bf16(dinv*relu(Agg(t1)+b1))
    k_gemm1<<<gT1, dim3(512), 0, stream>>>(x, wtb, dinv, t1b);
    k_gather8<true><<<gN8, blk, 0, stream>>>(csr_off, csr_src, dinv, t1b, b1,
                                             (unsigned int*)h1b);
    // conv2/3: fused Agg(h1) + both GEMMs
    k_gg2<<<gT, blk, 0, stream>>>(csr_off, csr_src, dinv, h1b, W2, b2, W3, b3, out);
}

// Round 11
// 152.068 us; speedup vs baseline: 18.1260x; 1.0414x over previous
//
// GCNEncoder MI355X kernel — v8: role-split fusion of GEMM1(MFMA) ∥ bscatter;
// unscaled t1b with per-edge dinv in gather1; 2-edge unrolled gathers.
#include <hip/hip_runtime.h>

#define NN 100000
#define NE 1600000
#define NB 391            // ceil(NN/256) buckets of 256 nodes (bucket = dst >> 8)
#define CHUNK 4096
#define NCHUNK 391        // ceil(NE/CHUNK)

typedef __attribute__((ext_vector_type(8))) short short8_t;
typedef __attribute__((ext_vector_type(4))) float float4_t;

// ---- bf16 helpers (RNE pack, bit-op unpack) ----
__device__ inline unsigned short f2bf(float f) {
    unsigned int u = __float_as_uint(f);
    unsigned int r = u + 0x7fffu + ((u >> 16) & 1u);
    return (unsigned short)(r >> 16);
}
__device__ inline float bf_lo(unsigned int u) { return __uint_as_float(u << 16); }
__device__ inline float bf_hi(unsigned int u) { return __uint_as_float(u & 0xffff0000u); }

// ---------------- Pass A: coarse histogram (LDS-privatized) ----------------
__global__ __launch_bounds__(256) void k_hist(const int* __restrict__ dst,
                                              int* __restrict__ bhist) {
    __shared__ int lh[NB];
    int t = threadIdx.x;
    for (int i = t; i < NB; i += 256) lh[i] = 0;
    __syncthreads();
    for (int e = blockIdx.x * 256 + t; e < NE; e += 256 * 256)
        atomicAdd(&lh[dst[e] >> 8], 1);
    __syncthreads();
    for (int i = t; i < NB; i += 256)
        if (lh[i]) atomicAdd(&bhist[i], lh[i]);
}

// ---------------- Pass B: scan buckets -> boff, bcursor ----------------
__global__ __launch_bounds__(256) void k_scanb(const int* __restrict__ bhist,
                                               int* __restrict__ boff,
                                               int* __restrict__ bcur) {
    __shared__ int sh[256];
    int t = threadIdx.x;
    int base = t * 2;
    int v0 = (base + 0 < NB) ? bhist[base + 0] : 0;
    int v1 = (base + 1 < NB) ? bhist[base + 1] : 0;
    int tsum = v0 + v1;
    sh[t] = tsum;
    __syncthreads();
    for (int d = 1; d < 256; d <<= 1) {
        int x = (t >= d) ? sh[t - d] : 0;
        __syncthreads();
        sh[t] += x;
        __syncthreads();
    }
    int excl = sh[t] - tsum;
    if (base + 0 < NB) { boff[base + 0] = excl;      bcur[base + 0] = excl; }
    if (base + 1 < NB) { boff[base + 1] = excl + v0; bcur[base + 1] = excl + v0; }
    if (t == 255) boff[NB] = sh[255];   // == NE
}

// ---------------- W1 transpose prekernel: wtb[c][k] = bf16(W1[k][c]) ----------------
__global__ __launch_bounds__(256) void k_w1t(const float* __restrict__ W1,
                                             unsigned short* __restrict__ wtb) {
    int f = blockIdx.x * 256 + threadIdx.x;      // 0..8191
    int c = f >> 7, k = f & 127;
    wtb[f] = f2bf(W1[k * 64 + c]);               // coalesced write, strided L2 read
}

// ---------------- FUSED: GEMM1 (MFMA, unscaled) ∥ bscatter ----------------
// blocks: b%3==2 -> bscatter chunk b/3 (391); else gemm1 tile 2*(b/3)+(b%3) (782).
// gemm1: t1b = bf16(x @ W1)  (NO dinv scale — applied per-edge in gather1)
// bscatter: packed word = src (17 bits) | local_dst (8 bits) << 17
__global__ __launch_bounds__(512) void k_fuse(const float* __restrict__ x,
                                              const unsigned short* __restrict__ wtb,
                                              unsigned short* __restrict__ t1b,
                                              const int* __restrict__ src,
                                              const int* __restrict__ dst,
                                              int* __restrict__ bcur,
                                              unsigned int* __restrict__ pairs) {
    __shared__ __align__(16) unsigned char smem[52224];
    const int b = blockIdx.x;
    const int t = threadIdx.x;

    if ((b % 3) == 2) {
        // ---- bscatter role ----
        int* lh    = (int*)smem;          // [NB]
        int* lbase = lh + NB;             // [NB]
        int e0 = (b / 3) * CHUNK;
        int e1 = min(e0 + CHUNK, NE);
        for (int i = t; i < NB; i += 512) lh[i] = 0;
        __syncthreads();
        for (int e = e0 + t; e < e1; e += 512)
            atomicAdd(&lh[dst[e] >> 8], 1);
        __syncthreads();
        int rot = (int)(((unsigned)(b / 3) * 97u) % NB);   // stagger atomic bursts
        for (int i = t; i < NB; i += 512) {
            int ii = i + rot; if (ii >= NB) ii -= NB;
            int h = lh[ii];
            lbase[ii] = h ? atomicAdd(&bcur[ii], h) : 0;
        }
        __syncthreads();
        for (int i = t; i < NB; i += 512) lh[i] = 0;   // reuse as cursor
        __syncthreads();
        for (int e = e0 + t; e < e1; e += 512) {
            int d = dst[e];
            int bk = d >> 8;
            int r = atomicAdd(&lh[bk], 1);
            pairs[lbase[bk] + r] = (unsigned int)src[e] | ((unsigned int)(d & 255) << 17);
        }
    } else {
        // ---- gemm1 role ----
        unsigned short* lx = (unsigned short*)smem;            // [128*136]
        unsigned short* lw = (unsigned short*)(smem + 34816);  // [64*136]
        const int tile = 2 * (b / 3) + (b % 3);
        const int row0 = tile * 128;
        const int nrows = min(128, NN - row0);

        #pragma unroll
        for (int i = 0; i < 8; ++i) {
            int f = t + i * 512;            // 0..4095
            int r = f >> 5, c4 = f & 31;
            float4 v = make_float4(0.f, 0.f, 0.f, 0.f);
            if (r < nrows) v = ((const float4*)(x + (size_t)(row0 + r) * 128))[c4];
            ushort4 o;
            o.x = f2bf(v.x); o.y = f2bf(v.y); o.z = f2bf(v.z); o.w = f2bf(v.w);
            *(ushort4*)&lx[r * 136 + c4 * 4] = o;
        }
        #pragma unroll
        for (int i = 0; i < 2; ++i) {
            int f = t + i * 512;            // 0..1023 ; f = c*16 + c8
            int c = f >> 4, c8 = f & 15;
            uint4 v = ((const uint4*)wtb)[f];
            *(uint4*)&lw[c * 136 + c8 * 8] = v;
        }
        __syncthreads();

        const int w = t >> 6, l = t & 63;
        const int m15 = l & 15, kg = l >> 4;
        const unsigned short* pa = &lx[(w * 16 + m15) * 136 + kg * 8];
        const unsigned short* pb = &lw[m15 * 136 + kg * 8];

        float4_t acc[4];
        #pragma unroll
        for (int cb = 0; cb < 4; ++cb) acc[cb] = (float4_t){0.f, 0.f, 0.f, 0.f};

        #pragma unroll
        for (int ks = 0; ks < 4; ++ks) {
            short8_t a = *(const short8_t*)(pa + ks * 32);
            #pragma unroll
            for (int cb = 0; cb < 4; ++cb) {
                short8_t bb = *(const short8_t*)(pb + cb * (16 * 136) + ks * 32);
                acc[cb] = __builtin_amdgcn_mfma_f32_16x16x32_bf16(a, bb, acc[cb], 0, 0, 0);
            }
        }

        #pragma unroll
        for (int r = 0; r < 4; ++r) {
            int lrow = w * 16 + kg * 4 + r;
            if (lrow < nrows) {
                size_t grow = (size_t)(row0 + lrow);
                #pragma unroll
                for (int cb = 0; cb < 4; ++cb)
                    t1b[grow * 64 + cb * 16 + m15] = f2bf(acc[cb][r]);
            }
        }
    }
}

// ---------------- Pass D: per-bucket fine sort + dinv + csr_off ----------------
__global__ __launch_bounds__(256) void k_fine(const unsigned int* __restrict__ pairs,
                                              const int* __restrict__ boff,
                                              int* __restrict__ csr_off,
                                              int* __restrict__ csr_src,
                                              float* __restrict__ dinv) {
    __shared__ int lcnt[256];
    __shared__ int sc[256];
    __shared__ int lofs[256];
    int t = threadIdx.x;
    int b = blockIdx.x;
    int n0 = b << 8;
    int nnode = min(256, NN - n0);
    int bO = boff[b], bE = boff[b + 1];

    lcnt[t] = 0;
    __syncthreads();
    for (int e = bO + t; e < bE; e += 256)
        atomicAdd(&lcnt[pairs[e] >> 17], 1);
    __syncthreads();
    sc[t] = lcnt[t];
    __syncthreads();
    for (int d = 1; d < 256; d <<= 1) {
        int x = (t >= d) ? sc[t - d] : 0;
        __syncthreads();
        sc[t] += x;
        __syncthreads();
    }
    {
        int excl = sc[t] - lcnt[t];
        lofs[t] = excl;
        if (t < nnode) {
            int n = n0 + t;
            csr_off[n] = bO + excl;
            dinv[n] = rsqrtf(1.0f + (float)lcnt[t]);
        }
        lcnt[t] = 0;   // reuse as cursor
    }
    if (b == NB - 1 && t == 0) csr_off[NN] = NE;
    __syncthreads();
    for (int e = bO + t; e < bE; e += 256) {
        unsigned int w = pairs[e];
        int li = (int)(w >> 17);
        int r = atomicAdd(&lcnt[li], 1);
        csr_src[bO + lofs[li] + r] = (int)(w & 0x1FFFFu);
    }
}

// ---------------- gather1: h1b = bf16( dinv[n]*relu( dinv[n]*acc + b1 ) ) ----------------
// acc = dinv[n]*t1[n] + sum_e dinv[s]*t1[s]   (t1b unscaled; 8 lanes/node, 8 ch/lane)
__global__ __launch_bounds__(256) void k_gather8(const int* __restrict__ off,
                                                 const int* __restrict__ csr,
                                                 const float* __restrict__ dinv,
                                                 const unsigned short* __restrict__ hb,
                                                 const float* __restrict__ bias,
                                                 unsigned int* __restrict__ outp) {
    int idx = blockIdx.x * 256 + threadIdx.x;   // 8 lanes per node
    int n = idx >> 3;
    if (n >= NN) return;
    int c8 = idx & 7;                           // channels c8*8 .. c8*8+7
    const uint4* h4 = (const uint4*)hb;         // row stride = 8 uint4 (64 bf16)
    float dn = dinv[n];
    float a0[8], a1[8];
    {
        uint4 v = h4[(size_t)n * 8 + c8];       // self term: dn * t1[n]
        a0[0] = dn * bf_lo(v.x); a0[1] = dn * bf_hi(v.x);
        a0[2] = dn * bf_lo(v.y); a0[3] = dn * bf_hi(v.y);
        a0[4] = dn * bf_lo(v.z); a0[5] = dn * bf_hi(v.z);
        a0[6] = dn * bf_lo(v.w); a0[7] = dn * bf_hi(v.w);
        #pragma unroll
        for (int j = 0; j < 8; ++j) a1[j] = 0.f;
    }
    int b = off[n], e = off[n + 1];
    int i = b;
    for (; i + 1 < e; i += 2) {                 // 2-edge unroll, dual accumulators
        int s0 = csr[i], s1 = csr[i + 1];
        float w0 = dinv[s0], w1 = dinv[s1];
        uint4 v0 = h4[(size_t)s0 * 8 + c8];
        uint4 v1 = h4[(size_t)s1 * 8 + c8];
        a0[0] += w0 * bf_lo(v0.x); a0[1] += w0 * bf_hi(v0.x);
        a0[2] += w0 * bf_lo(v0.y); a0[3] += w0 * bf_hi(v0.y);
        a0[4] += w0 * bf_lo(v0.z); a0[5] += w0 * bf_hi(v0.z);
        a0[6] += w0 * bf_lo(v0.w); a0[7] += w0 * bf_hi(v0.w);
        a1[0] += w1 * bf_lo(v1.x); a1[1] += w1 * bf_hi(v1.x);
        a1[2] += w1 * bf_lo(v1.y); a1[3] += w1 * bf_hi(v1.y);
        a1[4] += w1 * bf_lo(v1.z); a1[5] += w1 * bf_hi(v1.z);
        a1[6] += w1 * bf_lo(v1.w); a1[7] += w1 * bf_hi(v1.w);
    }
    if (i < e) {
        int s = csr[i];
        float w = dinv[s];
        uint4 v = h4[(size_t)s * 8 + c8];
        a0[0] += w * bf_lo(v.x); a0[1] += w * bf_hi(v.x);
        a0[2] += w * bf_lo(v.y); a0[3] += w * bf_hi(v.y);
        a0[4] += w * bf_lo(v.z); a0[5] += w * bf_hi(v.z);
        a0[6] += w * bf_lo(v.w); a0[7] += w * bf_hi(v.w);
    }
    float4 b0 = ((const float4*)bias)[c8 * 2];
    float4 b1v = ((const float4*)bias)[c8 * 2 + 1];
    float o[8];
    o[0] = dn * fmaxf(dn * (a0[0] + a1[0]) + b0.x, 0.f);
    o[1] = dn * fmaxf(dn * (a0[1] + a1[1]) + b0.y, 0.f);
    o[2] = dn * fmaxf(dn * (a0[2] + a1[2]) + b0.z, 0.f);
    o[3] = dn * fmaxf(dn * (a0[3] + a1[3]) + b0.w, 0.f);
    o[4] = dn * fmaxf(dn * (a0[4] + a1[4]) + b1v.x, 0.f);
    o[5] = dn * fmaxf(dn * (a0[5] + a1[5]) + b1v.y, 0.f);
    o[6] = dn * fmaxf(dn * (a0[6] + a1[6]) + b1v.z, 0.f);
    o[7] = dn * fmaxf(dn * (a0[7] + a1[7]) + b1v.w, 0.f);
    uint4 p;
    p.x = (unsigned int)f2bf(o[0]) | ((unsigned int)f2bf(o[1]) << 16);
    p.y = (unsigned int)f2bf(o[2]) | ((unsigned int)f2bf(o[3]) << 16);
    p.z = (unsigned int)f2bf(o[4]) | ((unsigned int)f2bf(o[5]) << 16);
    p.w = (unsigned int)f2bf(o[6]) | ((unsigned int)f2bf(o[7]) << 16);
    ((uint4*)outp)[(size_t)n * 8 + c8] = p;
}

// ---------------- Fused gather2 + GEMM2 (h1b prescaled) ----------------
__global__ __launch_bounds__(256) void k_gg2(const int* __restrict__ off,
                                             const int* __restrict__ csr,
                                             const float* __restrict__ dinv,
                                             const unsigned short* __restrict__ hb,
                                             const float* __restrict__ W2, const float* __restrict__ b2,
                                             const float* __restrict__ W3, const float* __restrict__ b3,
                                             float* __restrict__ out) {
    __shared__ float as_[64][72];     // +8 pad
    __shared__ float wc[64 * 64];
    __shared__ float bc[64];
    const int t = threadIdx.x;
    const int row0 = blockIdx.x * 64;
    const int nrows = min(64, NN - row0);

    #pragma unroll
    for (int i = 0; i < 16; ++i) {
        int f = t + i * 256;
        int k = f >> 6, c = f & 63;
        wc[f] = (c < 32) ? W2[k * 32 + c] : W3[k * 32 + (c - 32)];
    }
    if (t < 64) bc[t] = (t < 32) ? b2[t] : b3[t - 32];

    // phase A: gather agg2 rows straight into LDS (fp32), 2-edge unrolled
    {
        const int nl = t >> 2;              // 0..63
        const int n = row0 + nl;
        const int c16 = t & 3;              // channels c16*16 .. +15
        float acc[16];
        if (n < NN) {
            const uint4* h4 = (const uint4*)hb;
            float dn = dinv[n];
            size_t base = (size_t)n * 8 + c16 * 2;
            uint4 v0 = h4[base], v1 = h4[base + 1];
            acc[0]  = bf_lo(v0.x); acc[1]  = bf_hi(v0.x);
            acc[2]  = bf_lo(v0.y); acc[3]  = bf_hi(v0.y);
            acc[4]  = bf_lo(v0.z); acc[5]  = bf_hi(v0.z);
            acc[6]  = bf_lo(v0.w); acc[7]  = bf_hi(v0.w);
            acc[8]  = bf_lo(v1.x); acc[9]  = bf_hi(v1.x);
            acc[10] = bf_lo(v1.y); acc[11] = bf_hi(v1.y);
            acc[12] = bf_lo(v1.z); acc[13] = bf_hi(v1.z);
            acc[14] = bf_lo(v1.w); acc[15] = bf_hi(v1.w);
            int b = off[n], e = off[n + 1];
            int i = b;
            for (; i + 1 < e; i += 2) {
                int s0 = csr[i], s1 = csr[i + 1];
                size_t sb0 = (size_t)s0 * 8 + c16 * 2;
                size_t sb1 = (size_t)s1 * 8 + c16 * 2;
                uint4 w0 = h4[sb0], w1 = h4[sb0 + 1];
                uint4 u0 = h4[sb1], u1 = h4[sb1 + 1];
                acc[0]  += bf_lo(w0.x); acc[1]  += bf_hi(w0.x);
                acc[2]  += bf_lo(w0.y); acc[3]  += bf_hi(w0.y);
                acc[4]  += bf_lo(w0.z); acc[5]  += bf_hi(w0.z);
                acc[6]  += bf_lo(w0.w); acc[7]  += bf_hi(w0.w);
                acc[8]  += bf_lo(w1.x); acc[9]  += bf_hi(w1.x);
                acc[10] += bf_lo(w1.y); acc[11] += bf_hi(w1.y);
                acc[12] += bf_lo(w1.z); acc[13] += bf_hi(w1.z);
                acc[14] += bf_lo(w1.w); acc[15] += bf_hi(w1.w);
                acc[0]  += bf_lo(u0.x); acc[1]  += bf_hi(u0.x);
                acc[2]  += bf_lo(u0.y); acc[3]  += bf_hi(u0.y);
                acc[4]  += bf_lo(u0.z); acc[5]  += bf_hi(u0.z);
                acc[6]  += bf_lo(u0.w); acc[7]  += bf_hi(u0.w);
                acc[8]  += bf_lo(u1.x); acc[9]  += bf_hi(u1.x);
                acc[10] += bf_lo(u1.y); acc[11] += bf_hi(u1.y);
                acc[12] += bf_lo(u1.z); acc[13] += bf_hi(u1.z);
                acc[14] += bf_lo(u1.w); acc[15] += bf_hi(u1.w);
            }
            if (i < e) {
                size_t sb = (size_t)csr[i] * 8 + c16 * 2;
                uint4 w0 = h4[sb], w1 = h4[sb + 1];
                acc[0]  += bf_lo(w0.x); acc[1]  += bf_hi(w0.x);
                acc[2]  += bf_lo(w0.y); acc[3]  += bf_hi(w0.y);
                acc[4]  += bf_lo(w0.z); acc[5]  += bf_hi(w0.z);
                acc[6]  += bf_lo(w0.w); acc[7]  += bf_hi(w0.w);
                acc[8]  += bf_lo(w1.x); acc[9]  += bf_hi(w1.x);
                acc[10] += bf_lo(w1.y); acc[11] += bf_hi(w1.y);
                acc[12] += bf_lo(w1.z); acc[13] += bf_hi(w1.z);
                acc[14] += bf_lo(w1.w); acc[15] += bf_hi(w1.w);
            }
            #pragma unroll
            for (int j = 0; j < 16; ++j) acc[j] *= dn;
        } else {
            #pragma unroll
            for (int j = 0; j < 16; ++j) acc[j] = 0.f;
        }
        float* dp = &as_[nl][c16 * 16];
        #pragma unroll
        for (int j = 0; j < 16; ++j) dp[j] = acc[j];
    }
    __syncthreads();

    // phase B: GEMM
    const int tc = t & 15;
    const int tr = t >> 4;
    float acc[4][4];
    #pragma unroll
    for (int i = 0; i < 4; ++i)
        #pragma unroll
        for (int j = 0; j < 4; ++j) acc[i][j] = 0.f;

    #pragma unroll 4
    for (int k = 0; k < 64; ++k) {
        float4 wv = *(const float4*)&wc[k * 64 + tc * 4];
        #pragma unroll
        for (int i = 0; i < 4; ++i) {
            float xv = as_[tr * 4 + i][k];
            acc[i][0] += xv * wv.x; acc[i][1] += xv * wv.y;
            acc[i][2] += xv * wv.z; acc[i][3] += xv * wv.w;
        }
    }
    const int c0 = tc * 4;
    float4 bias = *(float4*)&bc[c0];
    #pragma unroll
    for (int i = 0; i < 4; ++i) {
        int r = tr * 4 + i;
        if (r < nrows) {
            float4 o = make_float4(acc[i][0] + bias.x, acc[i][1] + bias.y,
                                   acc[i][2] + bias.z, acc[i][3] + bias.w);
            size_t row = (size_t)(row0 + r);
            float* p = (tc < 8) ? (out + row * 32 + c0)
                                : (out + (size_t)NN * 32 + row * 32 + (c0 - 32));
            *(float4*)p = o;
        }
    }
}

extern "C" void kernel_launch(void* const* d_in, const int* in_sizes, int n_in,
                              void* d_out, int out_size, void* d_ws, size_t ws_size,
                              hipStream_t stream) {
    const float* x  = (const float*)d_in[0];
    const int* edges = (const int*)d_in[1];
    const float* W1 = (const float*)d_in[2];
    const float* b1 = (const float*)d_in[3];
    const float* W2 = (const float*)d_in[4];
    const float* b2 = (const float*)d_in[5];
    const float* W3 = (const float*)d_in[6];
    const float* b3 = (const float*)d_in[7];
    float* out = (float*)d_out;

    const int* srcs = edges;            // edges[0]
    const int* dsts = edges + NE;       // edges[1]

    // ws layout (4-byte words), total 8,205,280 words = 32.8 MB
    int*   csr_off = (int*)d_ws;                    // [NN+1]
    float* dinv    = (float*)((int*)d_ws + 100004); // [NN]
    int*   csr_src = (int*)d_ws + 200004;           // [NE]
    int*   bhist   = (int*)d_ws + 1800004;          // [NB]
    int*   boff    = (int*)d_ws + 1800396;          // [NB+1]
    int*   bcur    = (int*)d_ws + 1800788;          // [NB]
    unsigned short* wtb = (unsigned short*)((int*)d_ws + 1801184); // [64*128] bf16
    // region A: t1b [NN*64] bf16 — exclusive (written concurrently with pairs!)
    unsigned short* t1b = (unsigned short*)((int*)d_ws + 1805280); // 3.2e6 words
    // region B: pairs [NE uint] then h1b [NN*64] bf16 (pairs dead after k_fine)
    unsigned int*   pairs = (unsigned int*)((int*)d_ws + 5005280);
    unsigned short* h1b   = (unsigned short*)pairs;

    dim3 blk(256);
    const int gN8 = (NN * 8 + 255) / 256;   // 3125
    const int gT  = (NN + 63) / 64;         // 1563

    // prologue: histogram + W1 transpose + bucket scan
    hipMemsetAsync(bhist, 0, NB * sizeof(int), stream);
    k_hist<<<256, blk, 0, stream>>>(dsts, bhist);
    k_w1t<<<32, blk, 0, stream>>>(W1, wtb);
    k_scanb<<<1, blk, 0, stream>>>(bhist, boff, bcur);

    // fused: GEMM1 (782 tiles) ∥ bscatter (391 chunks), interleaved 2:1
    k_fuse<<<3 * NCHUNK, dim3(512), 0, stream>>>(x, wtb, t1b, srcs, dsts, bcur, pairs);

    k_fine<<<NB, blk, 0, stream>>>(pairs, boff, csr_off, csr_src, dinv);

    // conv1 aggregation: h1b = bf16(dinv*relu(dinv*Agg(t1)+b1))
    k_gather8<<<gN8, blk, 0, stream>>>(csr_off, csr_src, dinv, t1b, b1,
                                       (unsigned int*)h1b);
    // conv2/3: fused Agg(h1) + both GEMMs
    k_gg2<<<gT, blk, 0, stream>>>(csr_off, csr_src, dinv, h1b, W2, b2, W3, b3, out);
}